// Round 16
// baseline (357.460 us; speedup 1.0000x reference)
//
#include <hip/hip_runtime.h>

typedef _Float16 half8 __attribute__((ext_vector_type(8)));
typedef _Float16 half4v __attribute__((ext_vector_type(4)));
typedef float f32x4 __attribute__((ext_vector_type(4)));

#define NB 4
#define SQ 512
#define CL 3584
#define TT 4096
#define DM 2048
#define NH 16
#define DH 128

// XOR swizzles on half-index (attn LDS)
#define KSW(row, col) ((((row) * 128) + (col)) ^ ((((row) & 7) << 3)))
#define VSW(row, col) ((((row) * 64) + (col)) ^ ((((row) & 7) << 3)))
#define PSW(row, col) ((((row) * 64) + (col)) ^ ((((row) & 7) << 3)))

__device__ __forceinline__ void gl_lds16(const void* g, void* l) {
  __builtin_amdgcn_global_load_lds(
      (const __attribute__((address_space(1))) unsigned int*)g,
      (__attribute__((address_space(3))) unsigned int*)l, 16, 0, 0);
}

// ---------------- fp32 -> f16 dense convert, 6 slices in one launch ----------------
__global__ __launch_bounds__(256) void cvt_f16(
    const float* __restrict__ s0, const float* __restrict__ s1, const float* __restrict__ s2,
    const float* __restrict__ s3, const float* __restrict__ s4, const float* __restrict__ s5,
    _Float16* __restrict__ d0, _Float16* __restrict__ d1, _Float16* __restrict__ d2,
    _Float16* __restrict__ d3, _Float16* __restrict__ d4, _Float16* __restrict__ d5)
{
  const int z = blockIdx.y;
  const float* s = z == 0 ? s0 : z == 1 ? s1 : z == 2 ? s2 : z == 3 ? s3 : z == 4 ? s4 : s5;
  _Float16* d = z == 0 ? d0 : z == 1 ? d1 : z == 2 ? d2 : z == 3 ? d3 : z == 4 ? d4 : d5;
  const int n4 = DM * DM / 4;
  for (int v = blockIdx.x * blockDim.x + threadIdx.x; v < n4;
       v += gridDim.x * blockDim.x) {
    float4 x = ((const float4*)s)[v];
    half4v h = { (_Float16)x.x, (_Float16)x.y, (_Float16)x.z, (_Float16)x.w };
    ((half4v*)d)[v] = h;
  }
}

// single-matrix variant for wo (runs after attn; Qp region free)
__global__ __launch_bounds__(256) void cvt_f16_one(
    const float* __restrict__ s, _Float16* __restrict__ d)
{
  const int n4 = DM * DM / 4;
  for (int v = blockIdx.x * blockDim.x + threadIdx.x; v < n4;
       v += gridDim.x * blockDim.x) {
    float4 x = ((const float4*)s)[v];
    half4v h = { (_Float16)x.x, (_Float16)x.y, (_Float16)x.z, (_Float16)x.w };
    ((half4v*)d)[v] = h;
  }
}

// ---------------- cached K fp32 -> f16 convert over float4 range [v0, v1) ----------------
__global__ __launch_bounds__(256) void convert_Kpart(
    const float* __restrict__ ck, _Float16* __restrict__ K, long long v0, long long v1)
{
  const int pb = CL * DM / 4;
  for (long long v = v0 + (long long)blockIdx.x * blockDim.x + threadIdx.x; v < v1;
       v += (long long)gridDim.x * blockDim.x) {
    int b = (int)(v / pb);
    long long r = v - (long long)b * pb;
    float4 x = ((const float4*)ck)[v];
    half4v hx = { (_Float16)x.x, (_Float16)x.y, (_Float16)x.z, (_Float16)x.w };
    ((half4v*)K)[(long long)b * (TT * DM / 4) + r] = hx;
  }
}

// -- FUSED: QKV GEMM (bid<768) + cached-V transpose (bid<4352) + convK b2/b3 (bid>=4352) --
__global__ __launch_bounds__(512) void fused_pre(
    const _Float16* __restrict__ A0, const _Float16* __restrict__ A1,
    const _Float16* __restrict__ A2,
    const _Float16* __restrict__ W0, const _Float16* __restrict__ W1,
    const _Float16* __restrict__ W2,
    const float* __restrict__ b0, const float* __restrict__ b1,
    const float* __restrict__ b2,
    _Float16* __restrict__ Qp, _Float16* __restrict__ Kc,
    _Float16* __restrict__ Vt, const float* __restrict__ cv,
    const float* __restrict__ ck)
{
  __shared__ __align__(16) char smem[4 * 8192];

  const int bid = blockIdx.x;
  const int tid = threadIdx.x;

  if (bid < 768) {
    char* Abuf = smem;
    char* Wbuf = smem + 2 * 8192;
    const int bm = bid & 15, bn = (bid >> 4) & 15, z = bid >> 8;
    const _Float16* Ain = z == 0 ? A0 : z == 1 ? A1 : A2;
    const _Float16* W   = z == 0 ? W0 : z == 1 ? W1 : W2;
    const float* bias   = z == 0 ? b0 : z == 1 ? b1 : b2;

    const int wid = tid >> 6, lane = tid & 63;
    const int wm = wid >> 2, wn = wid & 3;
    const int lr = lane & 15, lg = lane >> 4;

    f32x4 acc[4][2];
#pragma unroll
    for (int i = 0; i < 4; ++i)
#pragma unroll
      for (int j = 0; j < 2; ++j) acc[i][j] = (f32x4){0.f, 0.f, 0.f, 0.f};

    size_t aoff, woff;
    {
      const int o = wid * 1024 + lane * 16;
      const int prow = o >> 7, pb = o & 127;
      const int lb = pb ^ ((prow & 7) << 4);
      const int r = (prow << 1) | (lb >> 6), c = lb & 63;
      aoff = (size_t)(bm * 128 + r) * 4096 + c;
      woff = (size_t)(bn * 128 + r) * 4096 + c;
    }

    auto stage = [&](int kt, int buf) {
      gl_lds16((const char*)Ain + aoff + kt * 64, Abuf + buf * 8192 + wid * 1024);
      gl_lds16((const char*)W + woff + kt * 64, Wbuf + buf * 8192 + wid * 1024);
    };
    auto lds_addr = [](const char* base, int r, int cb) -> const char* {
      return base + ((r >> 1) << 7) + ((((r & 1) << 6) | cb) ^ (((r >> 1) & 7) << 4));
    };
    auto compute = [&](int buf) {
      const char* ab = Abuf + buf * 8192;
      const char* wb = Wbuf + buf * 8192;
      half8 af[4], bf[2];
#pragma unroll
      for (int i = 0; i < 4; ++i)
        af[i] = *(const half8*)lds_addr(ab, wm * 64 + i * 16 + lr, lg << 4);
#pragma unroll
      for (int j = 0; j < 2; ++j)
        bf[j] = *(const half8*)lds_addr(wb, wn * 32 + j * 16 + lr, lg << 4);
#pragma unroll
      for (int i = 0; i < 4; ++i)
#pragma unroll
        for (int j = 0; j < 2; ++j)
          acc[i][j] = __builtin_amdgcn_mfma_f32_16x16x32_f16(af[i], bf[j], acc[i][j], 0, 0, 0);
    };

    const int NKT = DM / 32;
    stage(0, 0);
    __syncthreads();
    for (int kt = 0; kt < NKT; ++kt) {
      if (kt + 1 < NKT) stage(kt + 1, (kt + 1) & 1);
      compute(kt & 1);
      __syncthreads();
    }

    const float qscale = 0.08838834764831845f * 1.4426950408889634f;
#pragma unroll
    for (int i = 0; i < 4; ++i) {
      const int m0 = bm * 128 + wm * 64 + i * 16 + lg * 4;
#pragma unroll
      for (int j = 0; j < 2; ++j) {
        const int gn = bn * 128 + wn * 32 + j * 16 + lr;
        const float bb = bias[gn];
        if (z == 0) {
#pragma unroll
          for (int r = 0; r < 4; ++r)
            Qp[(size_t)(m0 + r) * DM + gn] = (_Float16)((acc[i][j][r] + bb) * qscale);
        } else if (z == 1) {
          const int b = m0 >> 9;
#pragma unroll
          for (int r = 0; r < 4; ++r)
            Kc[((size_t)b * TT + CL + ((m0 + r) & 511)) * DM + gn] =
                (_Float16)(acc[i][j][r] + bb);
        } else {
          half4v hv;
#pragma unroll
          for (int r = 0; r < 4; ++r) hv[r] = (_Float16)(acc[i][j][r] + bb);
          const int b = m0 >> 9, t = CL + (m0 & 511);
          const int h = gn >> 7, d = gn & 127;
          *(half4v*)&Vt[((size_t)(b * NH + h) * DH + d) * TT + t] = hv;
        }
      }
    }
  } else if (bid < 768 + 3584) {
    // ---------------- cached V transpose: 64t x 128dm tile ----------------
    _Float16 (*T)[136] = (_Float16(*)[136])smem;
    const int tv = bid - 768;
    const int b = tv / 896;
    const int rem = tv - b * 896;
    const int t0 = (rem % 56) * 64;
    const int dm0 = (rem / 56) * 128;
    {
      const int tr = tid >> 3, c0 = (tid & 7) * 16;
      const float* src = cv + ((size_t)b * CL + t0 + tr) * DM + dm0 + c0;
      float4 a0 = ((const float4*)src)[0];
      float4 a1 = ((const float4*)src)[1];
      float4 a2 = ((const float4*)src)[2];
      float4 a3 = ((const float4*)src)[3];
      half8 h0 = { (_Float16)a0.x, (_Float16)a0.y, (_Float16)a0.z, (_Float16)a0.w,
                   (_Float16)a1.x, (_Float16)a1.y, (_Float16)a1.z, (_Float16)a1.w };
      half8 h1 = { (_Float16)a2.x, (_Float16)a2.y, (_Float16)a2.z, (_Float16)a2.w,
                   (_Float16)a3.x, (_Float16)a3.y, (_Float16)a3.z, (_Float16)a3.w };
      *(half8*)&T[tr][c0] = h0;
      *(half8*)&T[tr][c0 + 8] = h1;
    }
    __syncthreads();
    {
      const int dl = tid >> 2, tc = (tid & 3) * 16;
      const int h = dm0 >> 7;
      half8 o0, o1;
#pragma unroll
      for (int i = 0; i < 8; ++i) o0[i] = T[tc + i][dl];
#pragma unroll
      for (int i = 0; i < 8; ++i) o1[i] = T[tc + 8 + i][dl];
      _Float16* dst = Vt + ((size_t)(b * NH + h) * DH + dl) * TT + t0 + tc;
      *(half8*)dst = o0;
      *(half8*)(dst + 8) = o1;
    }
  } else {
    // ---------------- cached K fp32->f16, batches 2..3 (big-ws path only) ----------------
    const int cb = bid - (768 + 3584);                 // 0..1023
    const int pb = CL * DM / 4;
    const long long nvec = (long long)NB * pb;
    const long long vhalf = 2LL * pb;                  // start of batch 2
    const long long stride = 1024LL * 512;
    for (long long v = vhalf + (long long)cb * 512 + tid; v < nvec; v += stride) {
      int b = (int)(v / pb);
      long long r = v - (long long)b * pb;
      float4 x = ((const float4*)ck)[v];
      half4v hx = { (_Float16)x.x, (_Float16)x.y, (_Float16)x.z, (_Float16)x.w };
      ((half4v*)Kc)[(long long)b * (TT * DM / 4) + r] = hx;
    }
  }
}

// ---------------- O-projection GEMM (f16 A via gl_lds, fp32 out) ----------------
__global__ __launch_bounds__(512, 4) void mm16o(
    const _Float16* __restrict__ Ain, const _Float16* __restrict__ W,
    const float* __restrict__ bias, float* __restrict__ Co)
{
  __shared__ __align__(16) char smem[4 * 8192];
  char* Abuf = smem;
  char* Wbuf = smem + 2 * 8192;

  const int tid = threadIdx.x;
  const int bm = blockIdx.x, bn = blockIdx.y;
  const int wid = tid >> 6, lane = tid & 63;
  const int wm = wid >> 2, wn = wid & 3;
  const int lr = lane & 15, lg = lane >> 4;

  f32x4 acc[4][2];
#pragma unroll
  for (int i = 0; i < 4; ++i)
#pragma unroll
    for (int j = 0; j < 2; ++j) acc[i][j] = (f32x4){0.f, 0.f, 0.f, 0.f};

  size_t aoff, woff;
  {
    const int o = wid * 1024 + lane * 16;
    const int prow = o >> 7, pb = o & 127;
    const int lb = pb ^ ((prow & 7) << 4);
    const int r = (prow << 1) | (lb >> 6), c = lb & 63;
    aoff = (size_t)(bm * 128 + r) * 4096 + c;
    woff = (size_t)(bn * 128 + r) * 4096 + c;
  }

  auto stage = [&](int kt, int buf) {
    gl_lds16((const char*)Ain + aoff + kt * 64, Abuf + buf * 8192 + wid * 1024);
    gl_lds16((const char*)W + woff + kt * 64, Wbuf + buf * 8192 + wid * 1024);
  };
  auto lds_addr = [](const char* base, int r, int cb) -> const char* {
    return base + ((r >> 1) << 7) + ((((r & 1) << 6) | cb) ^ (((r >> 1) & 7) << 4));
  };
  auto compute = [&](int buf) {
    const char* ab = Abuf + buf * 8192;
    const char* wb = Wbuf + buf * 8192;
    half8 af[4], bf[2];
#pragma unroll
    for (int i = 0; i < 4; ++i)
      af[i] = *(const half8*)lds_addr(ab, wm * 64 + i * 16 + lr, lg << 4);
#pragma unroll
    for (int j = 0; j < 2; ++j)
      bf[j] = *(const half8*)lds_addr(wb, wn * 32 + j * 16 + lr, lg << 4);
#pragma unroll
    for (int i = 0; i < 4; ++i)
#pragma unroll
      for (int j = 0; j < 2; ++j)
        acc[i][j] = __builtin_amdgcn_mfma_f32_16x16x32_f16(af[i], bf[j], acc[i][j], 0, 0, 0);
  };

  const int NKT = DM / 32;
  stage(0, 0);
  __syncthreads();
  for (int kt = 0; kt < NKT; ++kt) {
    if (kt + 1 < NKT) stage(kt + 1, (kt + 1) & 1);
    compute(kt & 1);
    __syncthreads();
  }

#pragma unroll
  for (int i = 0; i < 4; ++i) {
    const int m0 = bm * 128 + wm * 64 + i * 16 + lg * 4;
#pragma unroll
    for (int j = 0; j < 2; ++j) {
      const int gn = bn * 128 + wn * 32 + j * 16 + lr;
      const float bb = bias[gn];
#pragma unroll
      for (int r = 0; r < 4; ++r)
        Co[(size_t)(m0 + r) * DM + gn] = acc[i][j][r] + bb;
    }
  }
}

// ---------------- flash attention (R12 structure, ping-pong unrolled) ----------------
// 256 blocks, 512 threads = 8 waves x 32 q rows; KVB=64; kv-split x2.
// K dbuf + V tribuf + P = 112KB LDS. nt is always even (30 or 32).
__global__ __launch_bounds__(512) void attn_kernel(
    const _Float16* __restrict__ Qp, const _Float16* __restrict__ Kc,
    const _Float16* __restrict__ Vt, _Float16* __restrict__ O0,
    _Float16* __restrict__ O1, float2* __restrict__ ml)
{
  __shared__ _Float16 Ks[2][64 * 128];
  __shared__ _Float16 VTs[3][128 * 64];
  __shared__ _Float16 Ps[8][32 * 64];

  const int tid = threadIdx.x;
  const int lin = blockIdx.x;
  const int xcd = lin & 7, slot = lin >> 3;
  const int pair = xcd * 8 + (slot >> 2);
  const int rem = slot & 3;
  const int qb = rem >> 1, part = rem & 1;
  const int b = pair >> 4, h = pair & 15;

  const int wid = tid >> 6, lane = tid & 63;
  const int lr = lane & 15, lg = lane >> 4;
  const int qw = qb * 256 + wid * 32;

  half8 qf[2][4];
#pragma unroll
  for (int qs = 0; qs < 2; ++qs)
#pragma unroll
    for (int kk = 0; kk < 4; ++kk)
      qf[qs][kk] = *(const half8*)&Qp[(size_t)(b * SQ + qw + qs * 16 + lr) * DM +
                                      h * DH + kk * 32 + lg * 8];

  f32x4 zero = {0.f, 0.f, 0.f, 0.f};
  f32x4 acc[8][2];
#pragma unroll
  for (int d = 0; d < 8; ++d)
#pragma unroll
    for (int qs = 0; qs < 2; ++qs) acc[d][qs] = zero;
  float m_run[2] = {-1e30f, -1e30f}, l_run[2] = {0.f, 0.f};

  const int nt_full = (CL + qb * 256 + 256) / 64;   // 60 or 64
  const int halfn = nt_full >> 1;
  const int tbeg = part ? halfn : 0;
  const int nt = halfn;                              // both parts equal, even

  int ksrc[2], vsrc[2];
#pragma unroll
  for (int c = 0; c < 2; ++c) {
    const int p = c * 512 + wid * 64 + lane;
    { const int r = p >> 4, pg = p & 15, gc = pg ^ (r & 7);
      ksrc[c] = r * DM + gc * 8; }
    { const int d = p >> 3, pg = p & 7, gt = pg ^ (d & 7);
      vsrc[c] = d * TT + gt * 8; }
  }
  const _Float16* Kb = Kc + (size_t)b * TT * DM + h * DH;
  const _Float16* Vb = Vt + (size_t)(b * NH + h) * DH * TT;

  auto stage = [&](int tt, int kbuf, int vbuf) {
    const int t0 = (tbeg + tt) * 64;
#pragma unroll
    for (int c = 0; c < 2; ++c)
      gl_lds16(Kb + (size_t)t0 * DM + ksrc[c], &Ks[kbuf][(c * 512 + wid * 64) * 8]);
#pragma unroll
    for (int c = 0; c < 2; ++c)
      gl_lds16(Vb + t0 + vsrc[c], &VTs[vbuf][(c * 512 + wid * 64) * 8]);
  };

  auto qk = [&](int kbuf, f32x4 (*s)[2]) {
#pragma unroll
    for (int j = 0; j < 4; ++j)
#pragma unroll
      for (int qs = 0; qs < 2; ++qs) s[j][qs] = zero;
#pragma unroll
    for (int kk = 0; kk < 4; ++kk)
#pragma unroll
      for (int j = 0; j < 4; ++j) {
        half8 kb = *(const half8*)&Ks[kbuf][KSW(j * 16 + lr, kk * 32 + lg * 8)];
        s[j][0] = __builtin_amdgcn_mfma_f32_16x16x32_f16(kb, qf[0][kk], s[j][0], 0, 0, 0);
        s[j][1] = __builtin_amdgcn_mfma_f32_16x16x32_f16(kb, qf[1][kk], s[j][1], 0, 0, 0);
      }
  };

  auto mask_s = [&](int t0, f32x4 (*s)[2]) {
    if (part && t0 + 63 > CL + qw) {
#pragma unroll
      for (int j = 0; j < 4; ++j)
#pragma unroll
        for (int qs = 0; qs < 2; ++qs)
#pragma unroll
          for (int r = 0; r < 4; ++r)
            if (t0 + j * 16 + lg * 4 + r > CL + qw + qs * 16 + lr) s[j][qs][r] = -1e30f;
    }
  };

  auto softmax_step = [&](f32x4 (*s)[2]) {
    float mt[2];
#pragma unroll
    for (int qs = 0; qs < 2; ++qs) {
      float m = s[0][qs][0];
#pragma unroll
      for (int j = 0; j < 4; ++j)
#pragma unroll
        for (int r = 0; r < 4; ++r) m = fmaxf(m, s[j][qs][r]);
      mt[qs] = m;
    }
    if (!__all(mt[0] <= m_run[0] + 10.0f && mt[1] <= m_run[1] + 10.0f)) {
#pragma unroll
      for (int qs = 0; qs < 2; ++qs) {
        float m = fmaxf(mt[qs], __shfl_xor(mt[qs], 16));
        m = fmaxf(m, __shfl_xor(m, 32));
        const float mn = fmaxf(m_run[qs], m);
        const float fsc = exp2f(m_run[qs] - mn);
        m_run[qs] = mn;
        l_run[qs] *= fsc;
#pragma unroll
        for (int d = 0; d < 8; ++d)
#pragma unroll
          for (int r = 0; r < 4; ++r) acc[d][qs][r] *= fsc;
      }
    }
#pragma unroll
    for (int qs = 0; qs < 2; ++qs) {
      float ps = 0.f;
#pragma unroll
      for (int j = 0; j < 4; ++j) {
        float p0 = exp2f(s[j][qs][0] - m_run[qs]);
        float p1 = exp2f(s[j][qs][1] - m_run[qs]);
        float p2 = exp2f(s[j][qs][2] - m_run[qs]);
        float p3 = exp2f(s[j][qs][3] - m_run[qs]);
        ps += (p0 + p1) + (p2 + p3);
        half4v hp = { (_Float16)p0, (_Float16)p1, (_Float16)p2, (_Float16)p3 };
        *(half4v*)&Ps[wid][PSW(qs * 16 + lr, j * 16 + lg * 4)] = hp;
      }
      l_run[qs] += ps;
    }
  };

  auto pv = [&](int vbuf) {
#pragma unroll
    for (int kk = 0; kk < 2; ++kk) {
      half8 pf0 = *(const half8*)&Ps[wid][PSW(lr, kk * 32 + lg * 8)];
      half8 pf1 = *(const half8*)&Ps[wid][PSW(16 + lr, kk * 32 + lg * 8)];
#pragma unroll
      for (int d = 0; d < 8; ++d) {
        half8 vf = *(const half8*)&VTs[vbuf][VSW(d * 16 + lr, kk * 32 + lg * 8)];
        acc[d][0] = __builtin_amdgcn_mfma_f32_16x16x32_f16(vf, pf0, acc[d][0], 0, 0, 0);
        acc[d][1] = __builtin_amdgcn_mfma_f32_16x16x32_f16(vf, pf1, acc[d][1], 0, 0, 0);
      }
    }
  };

  f32x4 sA[4][2], sB[4][2];

  stage(0, 0, 0);
  __syncthreads();
  stage(1, 1, 1);
  qk(0, sA);
  mask_s(tbeg * 64, sA);

  int t = 1;
  for (; t + 1 < nt; t += 2) {
    __syncthreads();
    stage(t + 1, (t + 1) & 1, (t + 1) % 3);
    qk(t & 1, sB);
    softmax_step(sA);
    pv((t - 1) % 3);
    mask_s((tbeg + t) * 64, sB);

    __syncthreads();
    stage(t + 2, (t + 2) & 1, (t + 2) % 3);
    qk((t + 1) & 1, sA);
    softmax_step(sB);
    pv(t % 3);
    mask_s((tbeg + t + 1) * 64, sA);
  }
  // t == nt-1 (nt even)
  __syncthreads();
  qk(t & 1, sB);
  softmax_step(sA);
  pv((t - 1) % 3);
  mask_s((tbeg + t) * 64, sB);
  softmax_step(sB);
  pv(t % 3);

  _Float16* Od = part ? O1 : O0;
#pragma unroll
  for (int qs = 0; qs < 2; ++qs) {
    float lt = l_run[qs] + __shfl_xor(l_run[qs], 16);
    lt += __shfl_xor(lt, 32);
    const float inv = 1.0f / lt;
#pragma unroll
    for (int d = 0; d < 8; ++d) {
      half4v hv;
#pragma unroll
      for (int r = 0; r < 4; ++r) hv[r] = (_Float16)(acc[d][qs][r] * inv);
      *(half4v*)&Od[(size_t)(b * SQ + qw + qs * 16 + lr) * DM + h * DH + d * 16 + lg * 4] = hv;
    }
    if (lg == 0) {
      float2 e; e.x = m_run[qs]; e.y = lt;
      ml[part * (64 * SQ) + ((b * NH + h) * SQ) + qw + qs * 16 + lr] = e;
    }
  }
}

// ---------------- combine the two kv-partitions ----------------
__global__ __launch_bounds__(256) void combine(
    _Float16* __restrict__ AO, const _Float16* __restrict__ O1,
    const float2* __restrict__ ml)
{
  const int idx = blockIdx.x * 256 + threadIdx.x;
  const int row = idx >> 8;
  const int col0 = (idx & 255) * 8;
  const int b = row >> 9, q = row & 511, h = col0 >> 7;
  const float2 e0 = ml[(b * NH + h) * SQ + q];
  const float2 e1 = ml[64 * SQ + (b * NH + h) * SQ + q];
  const float m = fmaxf(e0.x, e1.x);
  float w0 = e0.y * exp2f(e0.x - m);
  float w1 = e1.y * exp2f(e1.x - m);
  const float inv = 1.0f / (w0 + w1);
  w0 *= inv; w1 *= inv;
  const size_t o = (size_t)row * DM + col0;
  half8 a = *(const half8*)&AO[o];
  half8 c = *(const half8*)&O1[o];
  half8 r;
#pragma unroll
  for (int i = 0; i < 8; ++i)
    r[i] = (_Float16)(w0 * (float)a[i] + w1 * (float)c[i]);
  *(half8*)&AO[o] = r;
}

extern "C" void kernel_launch(void* const* d_in, const int* in_sizes, int n_in,
                              void* d_out, int out_size, void* d_ws, size_t ws_size,
                              hipStream_t stream) {
  const float* query = (const float*)d_in[0];
  const float* key   = (const float*)d_in[1];
  const float* value = (const float*)d_in[2];
  const float* ck    = (const float*)d_in[3];
  const float* cv    = (const float*)d_in[4];
  const float* wq = (const float*)d_in[5];
  const float* bq = (const float*)d_in[6];
  const float* wk = (const float*)d_in[7];
  const float* bk = (const float*)d_in[8];
  const float* wv = (const float*)d_in[9];
  const float* bv = (const float*)d_in[10];
  const float* wo = (const float*)d_in[11];
  const float* bo = (const float*)d_in[12];

  char* ws = (char*)d_ws;
  _Float16* Kc = (_Float16*)ws;                 // 64 MiB: [4][4096][2048]
  _Float16* Vt = (_Float16*)(ws + 67108864);    // 64 MiB: [4][16][128][4096]
  _Float16* Qp = (_Float16*)(ws + 134217728);   // 8 MiB
  _Float16* AO = (_Float16*)(ws + 142606336);   // 8 MiB

  // input staging (dead regions): qh in AO; kh/vh in d_out (rewritten post-attn)
  _Float16* qh = AO;
  _Float16* kh = (_Float16*)d_out;
  _Float16* vh = (_Float16*)((char*)d_out + 8388608);
  _Float16* woh = Qp;  // converted post-attn

  _Float16* O1s = (_Float16*)d_out;                // 8 MiB
  float2* mls = (float2*)((char*)d_out + 8388608); // 512 KiB

  const long long pb4 = (long long)CL * DM / 4;
  const bool big = ws_size >= (size_t)153 * 1024 * 1024;

  if (big) {
    // weights: wq at ws+144MiB; wk/wv in Kc cache stripes of batches 0/1.
    // Batches 2/3 of convK are fused into fused_pre (their stripes are free);
    // batches 0/1 convert serially afterwards (weights dead by then).
    _Float16* wqh = (_Float16*)(ws + 150994944);   // 8 MiB at ws+144MiB
    _Float16* wkh = Kc;                            // b0 cache stripe
    _Float16* wvh = Kc + (size_t)TT * DM;          // b1 cache stripe
    cvt_f16<<<dim3(512, 6), 256, 0, stream>>>(
        query, key, value, wq, wk, wv, qh, kh, vh, wqh, wkh, wvh);
    fused_pre<<<768 + 3584 + 1024, 512, 0, stream>>>(
        qh, kh, vh, wqh, wkh, wvh, bq, bk, bv, Qp, Kc, Vt, cv, ck);
    convert_Kpart<<<1024, 256, 0, stream>>>(ck, Kc, 0, 2 * pb4);
  } else {
    // R12 layout: weights in Kc stripes b0/b1/b2; full convK after fused_pre.
    _Float16* wqh = Kc;
    _Float16* wkh = (_Float16*)(ws + 16777216);
    _Float16* wvh = (_Float16*)(ws + 33554432);
    cvt_f16<<<dim3(512, 6), 256, 0, stream>>>(
        query, key, value, wq, wk, wv, qh, kh, vh, wqh, wkh, wvh);
    fused_pre<<<768 + 3584, 512, 0, stream>>>(
        qh, kh, vh, wqh, wkh, wvh, bq, bk, bv, Qp, Kc, Vt, cv, ck);
    convert_Kpart<<<2048, 256, 0, stream>>>(ck, Kc, 0, 4 * pb4);
  }

  attn_kernel<<<256, 512, 0, stream>>>(Qp, Kc, Vt, AO, O1s, mls);
  combine<<<2048, 256, 0, stream>>>(AO, O1s, mls);
  cvt_f16_one<<<512, 256, 0, stream>>>(wo, woh);
  mm16o<<<dim3(16, 16), 512, 0, stream>>>(AO, woh, bo, (float*)d_out);
}

// Round 17
// 317.689 us; speedup vs baseline: 1.1252x; 1.1252x over previous
//
#include <hip/hip_runtime.h>

typedef _Float16 half8 __attribute__((ext_vector_type(8)));
typedef _Float16 half4v __attribute__((ext_vector_type(4)));
typedef float f32x4 __attribute__((ext_vector_type(4)));

#define NB 4
#define SQ 512
#define CL 3584
#define TT 4096
#define DM 2048
#define NH 16
#define DH 128

// XOR swizzles on half-index (attn LDS)
#define KSW(row, col) ((((row) * 128) + (col)) ^ ((((row) & 7) << 3)))
#define VSW(row, col) ((((row) * 64) + (col)) ^ ((((row) & 7) << 3)))
#define PSW(row, col) ((((row) * 64) + (col)) ^ ((((row) & 7) << 3)))

__device__ __forceinline__ void gl_lds16(const void* g, void* l) {
  __builtin_amdgcn_global_load_lds(
      (const __attribute__((address_space(1))) unsigned int*)g,
      (__attribute__((address_space(3))) unsigned int*)l, 16, 0, 0);
}

// ---------------- fp32 -> f16 dense convert, 6 slices in one launch ----------------
__global__ __launch_bounds__(256) void cvt_f16(
    const float* __restrict__ s0, const float* __restrict__ s1, const float* __restrict__ s2,
    const float* __restrict__ s3, const float* __restrict__ s4, const float* __restrict__ s5,
    _Float16* __restrict__ d0, _Float16* __restrict__ d1, _Float16* __restrict__ d2,
    _Float16* __restrict__ d3, _Float16* __restrict__ d4, _Float16* __restrict__ d5)
{
  const int z = blockIdx.y;
  const float* s = z == 0 ? s0 : z == 1 ? s1 : z == 2 ? s2 : z == 3 ? s3 : z == 4 ? s4 : s5;
  _Float16* d = z == 0 ? d0 : z == 1 ? d1 : z == 2 ? d2 : z == 3 ? d3 : z == 4 ? d4 : d5;
  const int n4 = DM * DM / 4;
  for (int v = blockIdx.x * blockDim.x + threadIdx.x; v < n4;
       v += gridDim.x * blockDim.x) {
    float4 x = ((const float4*)s)[v];
    half4v h = { (_Float16)x.x, (_Float16)x.y, (_Float16)x.z, (_Float16)x.w };
    ((half4v*)d)[v] = h;
  }
}

// single-matrix variant for wo (runs after attn; Qp region free)
__global__ __launch_bounds__(256) void cvt_f16_one(
    const float* __restrict__ s, _Float16* __restrict__ d)
{
  const int n4 = DM * DM / 4;
  for (int v = blockIdx.x * blockDim.x + threadIdx.x; v < n4;
       v += gridDim.x * blockDim.x) {
    float4 x = ((const float4*)s)[v];
    half4v h = { (_Float16)x.x, (_Float16)x.y, (_Float16)x.z, (_Float16)x.w };
    ((half4v*)d)[v] = h;
  }
}

// ---------------- cached K fp32 -> f16 convert over float4 range [v0, v1) ----------------
__global__ __launch_bounds__(256) void convert_Kpart(
    const float* __restrict__ ck, _Float16* __restrict__ K, long long v0, long long v1)
{
  const int pb = CL * DM / 4;
  for (long long v = v0 + (long long)blockIdx.x * blockDim.x + threadIdx.x; v < v1;
       v += (long long)gridDim.x * blockDim.x) {
    int b = (int)(v / pb);
    long long r = v - (long long)b * pb;
    float4 x = ((const float4*)ck)[v];
    half4v hx = { (_Float16)x.x, (_Float16)x.y, (_Float16)x.z, (_Float16)x.w };
    ((half4v*)K)[(long long)b * (TT * DM / 4) + r] = hx;
  }
}

// -- FUSED: QKV GEMM (bid<768) + cached-V transpose (bid<4352) + convK b2/b3 (bid>=4352) --
__global__ __launch_bounds__(512) void fused_pre(
    const _Float16* __restrict__ A0, const _Float16* __restrict__ A1,
    const _Float16* __restrict__ A2,
    const _Float16* __restrict__ W0, const _Float16* __restrict__ W1,
    const _Float16* __restrict__ W2,
    const float* __restrict__ b0, const float* __restrict__ b1,
    const float* __restrict__ b2,
    _Float16* __restrict__ Qp, _Float16* __restrict__ Kc,
    _Float16* __restrict__ Vt, const float* __restrict__ cv,
    const float* __restrict__ ck)
{
  __shared__ __align__(16) char smem[4 * 8192];

  const int bid = blockIdx.x;
  const int tid = threadIdx.x;

  if (bid < 768) {
    char* Abuf = smem;
    char* Wbuf = smem + 2 * 8192;
    const int bm = bid & 15, bn = (bid >> 4) & 15, z = bid >> 8;
    const _Float16* Ain = z == 0 ? A0 : z == 1 ? A1 : A2;
    const _Float16* W   = z == 0 ? W0 : z == 1 ? W1 : W2;
    const float* bias   = z == 0 ? b0 : z == 1 ? b1 : b2;

    const int wid = tid >> 6, lane = tid & 63;
    const int wm = wid >> 2, wn = wid & 3;
    const int lr = lane & 15, lg = lane >> 4;

    f32x4 acc[4][2];
#pragma unroll
    for (int i = 0; i < 4; ++i)
#pragma unroll
      for (int j = 0; j < 2; ++j) acc[i][j] = (f32x4){0.f, 0.f, 0.f, 0.f};

    size_t aoff, woff;
    {
      const int o = wid * 1024 + lane * 16;
      const int prow = o >> 7, pb = o & 127;
      const int lb = pb ^ ((prow & 7) << 4);
      const int r = (prow << 1) | (lb >> 6), c = lb & 63;
      aoff = (size_t)(bm * 128 + r) * 4096 + c;
      woff = (size_t)(bn * 128 + r) * 4096 + c;
    }

    auto stage = [&](int kt, int buf) {
      gl_lds16((const char*)Ain + aoff + kt * 64, Abuf + buf * 8192 + wid * 1024);
      gl_lds16((const char*)W + woff + kt * 64, Wbuf + buf * 8192 + wid * 1024);
    };
    auto lds_addr = [](const char* base, int r, int cb) -> const char* {
      return base + ((r >> 1) << 7) + ((((r & 1) << 6) | cb) ^ (((r >> 1) & 7) << 4));
    };
    auto compute = [&](int buf) {
      const char* ab = Abuf + buf * 8192;
      const char* wb = Wbuf + buf * 8192;
      half8 af[4], bf[2];
#pragma unroll
      for (int i = 0; i < 4; ++i)
        af[i] = *(const half8*)lds_addr(ab, wm * 64 + i * 16 + lr, lg << 4);
#pragma unroll
      for (int j = 0; j < 2; ++j)
        bf[j] = *(const half8*)lds_addr(wb, wn * 32 + j * 16 + lr, lg << 4);
#pragma unroll
      for (int i = 0; i < 4; ++i)
#pragma unroll
        for (int j = 0; j < 2; ++j)
          acc[i][j] = __builtin_amdgcn_mfma_f32_16x16x32_f16(af[i], bf[j], acc[i][j], 0, 0, 0);
    };

    const int NKT = DM / 32;
    stage(0, 0);
    __syncthreads();
    for (int kt = 0; kt < NKT; ++kt) {
      if (kt + 1 < NKT) stage(kt + 1, (kt + 1) & 1);
      compute(kt & 1);
      __syncthreads();
    }

    const float qscale = 0.08838834764831845f * 1.4426950408889634f;
#pragma unroll
    for (int i = 0; i < 4; ++i) {
      const int m0 = bm * 128 + wm * 64 + i * 16 + lg * 4;
#pragma unroll
      for (int j = 0; j < 2; ++j) {
        const int gn = bn * 128 + wn * 32 + j * 16 + lr;
        const float bb = bias[gn];
        if (z == 0) {
#pragma unroll
          for (int r = 0; r < 4; ++r)
            Qp[(size_t)(m0 + r) * DM + gn] = (_Float16)((acc[i][j][r] + bb) * qscale);
        } else if (z == 1) {
          const int b = m0 >> 9;
#pragma unroll
          for (int r = 0; r < 4; ++r)
            Kc[((size_t)b * TT + CL + ((m0 + r) & 511)) * DM + gn] =
                (_Float16)(acc[i][j][r] + bb);
        } else {
          half4v hv;
#pragma unroll
          for (int r = 0; r < 4; ++r) hv[r] = (_Float16)(acc[i][j][r] + bb);
          const int b = m0 >> 9, t = CL + (m0 & 511);
          const int h = gn >> 7, d = gn & 127;
          *(half4v*)&Vt[((size_t)(b * NH + h) * DH + d) * TT + t] = hv;
        }
      }
    }
  } else if (bid < 768 + 3584) {
    // ---------------- cached V transpose: 64t x 128dm tile ----------------
    _Float16 (*T)[136] = (_Float16(*)[136])smem;
    const int tv = bid - 768;
    const int b = tv / 896;
    const int rem = tv - b * 896;
    const int t0 = (rem % 56) * 64;
    const int dm0 = (rem / 56) * 128;
    {
      const int tr = tid >> 3, c0 = (tid & 7) * 16;
      const float* src = cv + ((size_t)b * CL + t0 + tr) * DM + dm0 + c0;
      float4 a0 = ((const float4*)src)[0];
      float4 a1 = ((const float4*)src)[1];
      float4 a2 = ((const float4*)src)[2];
      float4 a3 = ((const float4*)src)[3];
      half8 h0 = { (_Float16)a0.x, (_Float16)a0.y, (_Float16)a0.z, (_Float16)a0.w,
                   (_Float16)a1.x, (_Float16)a1.y, (_Float16)a1.z, (_Float16)a1.w };
      half8 h1 = { (_Float16)a2.x, (_Float16)a2.y, (_Float16)a2.z, (_Float16)a2.w,
                   (_Float16)a3.x, (_Float16)a3.y, (_Float16)a3.z, (_Float16)a3.w };
      *(half8*)&T[tr][c0] = h0;
      *(half8*)&T[tr][c0 + 8] = h1;
    }
    __syncthreads();
    {
      const int dl = tid >> 2, tc = (tid & 3) * 16;
      const int h = dm0 >> 7;
      half8 o0, o1;
#pragma unroll
      for (int i = 0; i < 8; ++i) o0[i] = T[tc + i][dl];
#pragma unroll
      for (int i = 0; i < 8; ++i) o1[i] = T[tc + 8 + i][dl];
      _Float16* dst = Vt + ((size_t)(b * NH + h) * DH + dl) * TT + t0 + tc;
      *(half8*)dst = o0;
      *(half8*)(dst + 8) = o1;
    }
  } else {
    // ---------------- cached K fp32->f16, batches 2..3 (big-ws path only) ----------------
    const int cb = bid - (768 + 3584);                 // 0..1023
    const int pb = CL * DM / 4;
    const long long nvec = (long long)NB * pb;
    const long long vhalf = 2LL * pb;                  // start of batch 2
    const long long stride = 1024LL * 512;
    for (long long v = vhalf + (long long)cb * 512 + tid; v < nvec; v += stride) {
      int b = (int)(v / pb);
      long long r = v - (long long)b * pb;
      float4 x = ((const float4*)ck)[v];
      half4v hx = { (_Float16)x.x, (_Float16)x.y, (_Float16)x.z, (_Float16)x.w };
      ((half4v*)Kc)[(long long)b * (TT * DM / 4) + r] = hx;
    }
  }
}

// ---------------- O-projection GEMM (f16 A via gl_lds, fp32 out) ----------------
__global__ __launch_bounds__(512, 4) void mm16o(
    const _Float16* __restrict__ Ain, const _Float16* __restrict__ W,
    const float* __restrict__ bias, float* __restrict__ Co)
{
  __shared__ __align__(16) char smem[4 * 8192];
  char* Abuf = smem;
  char* Wbuf = smem + 2 * 8192;

  const int tid = threadIdx.x;
  const int bm = blockIdx.x, bn = blockIdx.y;
  const int wid = tid >> 6, lane = tid & 63;
  const int wm = wid >> 2, wn = wid & 3;
  const int lr = lane & 15, lg = lane >> 4;

  f32x4 acc[4][2];
#pragma unroll
  for (int i = 0; i < 4; ++i)
#pragma unroll
    for (int j = 0; j < 2; ++j) acc[i][j] = (f32x4){0.f, 0.f, 0.f, 0.f};

  size_t aoff, woff;
  {
    const int o = wid * 1024 + lane * 16;
    const int prow = o >> 7, pb = o & 127;
    const int lb = pb ^ ((prow & 7) << 4);
    const int r = (prow << 1) | (lb >> 6), c = lb & 63;
    aoff = (size_t)(bm * 128 + r) * 4096 + c;
    woff = (size_t)(bn * 128 + r) * 4096 + c;
  }

  auto stage = [&](int kt, int buf) {
    gl_lds16((const char*)Ain + aoff + kt * 64, Abuf + buf * 8192 + wid * 1024);
    gl_lds16((const char*)W + woff + kt * 64, Wbuf + buf * 8192 + wid * 1024);
  };
  auto lds_addr = [](const char* base, int r, int cb) -> const char* {
    return base + ((r >> 1) << 7) + ((((r & 1) << 6) | cb) ^ (((r >> 1) & 7) << 4));
  };
  auto compute = [&](int buf) {
    const char* ab = Abuf + buf * 8192;
    const char* wb = Wbuf + buf * 8192;
    half8 af[4], bf[2];
#pragma unroll
    for (int i = 0; i < 4; ++i)
      af[i] = *(const half8*)lds_addr(ab, wm * 64 + i * 16 + lr, lg << 4);
#pragma unroll
    for (int j = 0; j < 2; ++j)
      bf[j] = *(const half8*)lds_addr(wb, wn * 32 + j * 16 + lr, lg << 4);
#pragma unroll
    for (int i = 0; i < 4; ++i)
#pragma unroll
      for (int j = 0; j < 2; ++j)
        acc[i][j] = __builtin_amdgcn_mfma_f32_16x16x32_f16(af[i], bf[j], acc[i][j], 0, 0, 0);
  };

  const int NKT = DM / 32;
  stage(0, 0);
  __syncthreads();
  for (int kt = 0; kt < NKT; ++kt) {
    if (kt + 1 < NKT) stage(kt + 1, (kt + 1) & 1);
    compute(kt & 1);
    __syncthreads();
  }

#pragma unroll
  for (int i = 0; i < 4; ++i) {
    const int m0 = bm * 128 + wm * 64 + i * 16 + lg * 4;
#pragma unroll
    for (int j = 0; j < 2; ++j) {
      const int gn = bn * 128 + wn * 32 + j * 16 + lr;
      const float bb = bias[gn];
#pragma unroll
      for (int r = 0; r < 4; ++r)
        Co[(size_t)(m0 + r) * DM + gn] = acc[i][j][r] + bb;
    }
  }
}

// ---------------- flash attention (R12-proven: kv-split x2, pipelined) ----------------
__global__ __launch_bounds__(512) void attn_kernel(
    const _Float16* __restrict__ Qp, const _Float16* __restrict__ Kc,
    const _Float16* __restrict__ Vt, _Float16* __restrict__ O0,
    _Float16* __restrict__ O1, float2* __restrict__ ml)
{
  __shared__ _Float16 Ks[2][64 * 128];
  __shared__ _Float16 VTs[3][128 * 64];
  __shared__ _Float16 Ps[8][32 * 64];

  const int tid = threadIdx.x;
  const int lin = blockIdx.x;
  const int xcd = lin & 7, slot = lin >> 3;
  const int pair = xcd * 8 + (slot >> 2);
  const int rem = slot & 3;
  const int qb = rem >> 1, part = rem & 1;
  const int b = pair >> 4, h = pair & 15;

  const int wid = tid >> 6, lane = tid & 63;
  const int lr = lane & 15, lg = lane >> 4;
  const int qw = qb * 256 + wid * 32;

  half8 qf[2][4];
#pragma unroll
  for (int qs = 0; qs < 2; ++qs)
#pragma unroll
    for (int kk = 0; kk < 4; ++kk)
      qf[qs][kk] = *(const half8*)&Qp[(size_t)(b * SQ + qw + qs * 16 + lr) * DM +
                                      h * DH + kk * 32 + lg * 8];

  f32x4 zero = {0.f, 0.f, 0.f, 0.f};
  f32x4 acc[8][2];
#pragma unroll
  for (int d = 0; d < 8; ++d)
#pragma unroll
    for (int qs = 0; qs < 2; ++qs) acc[d][qs] = zero;
  float m_run[2] = {-1e30f, -1e30f}, l_run[2] = {0.f, 0.f};

  const int nt_full = (CL + qb * 256 + 256) / 64;
  const int halfn = nt_full >> 1;
  const int tbeg = part ? halfn : 0;
  const int nt = part ? (nt_full - halfn) : halfn;

  int ksrc[2], vsrc[2];
#pragma unroll
  for (int c = 0; c < 2; ++c) {
    const int p = c * 512 + wid * 64 + lane;
    { const int r = p >> 4, pg = p & 15, gc = pg ^ (r & 7);
      ksrc[c] = r * DM + gc * 8; }
    { const int d = p >> 3, pg = p & 7, gt = pg ^ (d & 7);
      vsrc[c] = d * TT + gt * 8; }
  }
  const _Float16* Kb = Kc + (size_t)b * TT * DM + h * DH;
  const _Float16* Vb = Vt + (size_t)(b * NH + h) * DH * TT;

  auto stage = [&](int tt, int kbuf, int vbuf) {
    const int t0 = (tbeg + tt) * 64;
#pragma unroll
    for (int c = 0; c < 2; ++c)
      gl_lds16(Kb + (size_t)t0 * DM + ksrc[c], &Ks[kbuf][(c * 512 + wid * 64) * 8]);
#pragma unroll
    for (int c = 0; c < 2; ++c)
      gl_lds16(Vb + t0 + vsrc[c], &VTs[vbuf][(c * 512 + wid * 64) * 8]);
  };

  auto qk = [&](int kbuf, f32x4 (*s)[2]) {
#pragma unroll
    for (int j = 0; j < 4; ++j)
#pragma unroll
      for (int qs = 0; qs < 2; ++qs) s[j][qs] = zero;
#pragma unroll
    for (int kk = 0; kk < 4; ++kk)
#pragma unroll
      for (int j = 0; j < 4; ++j) {
        half8 kb = *(const half8*)&Ks[kbuf][KSW(j * 16 + lr, kk * 32 + lg * 8)];
        s[j][0] = __builtin_amdgcn_mfma_f32_16x16x32_f16(kb, qf[0][kk], s[j][0], 0, 0, 0);
        s[j][1] = __builtin_amdgcn_mfma_f32_16x16x32_f16(kb, qf[1][kk], s[j][1], 0, 0, 0);
      }
  };

  auto mask_s = [&](int t0, f32x4 (*s)[2]) {
    if (part && t0 + 63 > CL + qw) {
#pragma unroll
      for (int j = 0; j < 4; ++j)
#pragma unroll
        for (int qs = 0; qs < 2; ++qs)
#pragma unroll
          for (int r = 0; r < 4; ++r)
            if (t0 + j * 16 + lg * 4 + r > CL + qw + qs * 16 + lr) s[j][qs][r] = -1e30f;
    }
  };

  auto softmax_step = [&](f32x4 (*s)[2]) {
    float mt[2];
#pragma unroll
    for (int qs = 0; qs < 2; ++qs) {
      float m = s[0][qs][0];
#pragma unroll
      for (int j = 0; j < 4; ++j)
#pragma unroll
        for (int r = 0; r < 4; ++r) m = fmaxf(m, s[j][qs][r]);
      mt[qs] = m;
    }
    if (!__all(mt[0] <= m_run[0] + 10.0f && mt[1] <= m_run[1] + 10.0f)) {
#pragma unroll
      for (int qs = 0; qs < 2; ++qs) {
        float m = fmaxf(mt[qs], __shfl_xor(mt[qs], 16));
        m = fmaxf(m, __shfl_xor(m, 32));
        const float mn = fmaxf(m_run[qs], m);
        const float fsc = exp2f(m_run[qs] - mn);
        m_run[qs] = mn;
        l_run[qs] *= fsc;
#pragma unroll
        for (int d = 0; d < 8; ++d)
#pragma unroll
          for (int r = 0; r < 4; ++r) acc[d][qs][r] *= fsc;
      }
    }
#pragma unroll
    for (int qs = 0; qs < 2; ++qs) {
      float ps = 0.f;
#pragma unroll
      for (int j = 0; j < 4; ++j) {
        float p0 = exp2f(s[j][qs][0] - m_run[qs]);
        float p1 = exp2f(s[j][qs][1] - m_run[qs]);
        float p2 = exp2f(s[j][qs][2] - m_run[qs]);
        float p3 = exp2f(s[j][qs][3] - m_run[qs]);
        ps += (p0 + p1) + (p2 + p3);
        half4v hp = { (_Float16)p0, (_Float16)p1, (_Float16)p2, (_Float16)p3 };
        *(half4v*)&Ps[wid][PSW(qs * 16 + lr, j * 16 + lg * 4)] = hp;
      }
      l_run[qs] += ps;
    }
  };

  auto pv = [&](int vbuf) {
#pragma unroll
    for (int kk = 0; kk < 2; ++kk) {
      half8 pf0 = *(const half8*)&Ps[wid][PSW(lr, kk * 32 + lg * 8)];
      half8 pf1 = *(const half8*)&Ps[wid][PSW(16 + lr, kk * 32 + lg * 8)];
#pragma unroll
      for (int d = 0; d < 8; ++d) {
        half8 vf = *(const half8*)&VTs[vbuf][VSW(d * 16 + lr, kk * 32 + lg * 8)];
        acc[d][0] = __builtin_amdgcn_mfma_f32_16x16x32_f16(vf, pf0, acc[d][0], 0, 0, 0);
        acc[d][1] = __builtin_amdgcn_mfma_f32_16x16x32_f16(vf, pf1, acc[d][1], 0, 0, 0);
      }
    }
  };

  f32x4 sp[4][2], sc[4][2];

  stage(0, 0, 0);
  __syncthreads();
  stage(1, 1, 1);
  qk(0, sp);
  mask_s(tbeg * 64, sp);

  for (int t = 1; t < nt; ++t) {
    __syncthreads();
    if (t + 1 < nt) stage(t + 1, (t + 1) & 1, (t + 1) % 3);
    qk(t & 1, sc);
    softmax_step(sp);
    pv((t - 1) % 3);
    mask_s((tbeg + t) * 64, sc);
#pragma unroll
    for (int j = 0; j < 4; ++j)
#pragma unroll
      for (int qs = 0; qs < 2; ++qs) sp[j][qs] = sc[j][qs];
  }
  softmax_step(sp);
  pv((nt - 1) % 3);

  _Float16* Od = part ? O1 : O0;
#pragma unroll
  for (int qs = 0; qs < 2; ++qs) {
    float lt = l_run[qs] + __shfl_xor(l_run[qs], 16);
    lt += __shfl_xor(lt, 32);
    const float inv = 1.0f / lt;
#pragma unroll
    for (int d = 0; d < 8; ++d) {
      half4v hv;
#pragma unroll
      for (int r = 0; r < 4; ++r) hv[r] = (_Float16)(acc[d][qs][r] * inv);
      *(half4v*)&Od[(size_t)(b * SQ + qw + qs * 16 + lr) * DM + h * DH + d * 16 + lg * 4] = hv;
    }
    if (lg == 0) {
      float2 e; e.x = m_run[qs]; e.y = lt;
      ml[part * (64 * SQ) + ((b * NH + h) * SQ) + qw + qs * 16 + lr] = e;
    }
  }
}

// ---------------- combine the two kv-partitions ----------------
__global__ __launch_bounds__(256) void combine(
    _Float16* __restrict__ AO, const _Float16* __restrict__ O1,
    const float2* __restrict__ ml)
{
  const int idx = blockIdx.x * 256 + threadIdx.x;
  const int row = idx >> 8;
  const int col0 = (idx & 255) * 8;
  const int b = row >> 9, q = row & 511, h = col0 >> 7;
  const float2 e0 = ml[(b * NH + h) * SQ + q];
  const float2 e1 = ml[64 * SQ + (b * NH + h) * SQ + q];
  const float m = fmaxf(e0.x, e1.x);
  float w0 = e0.y * exp2f(e0.x - m);
  float w1 = e1.y * exp2f(e1.x - m);
  const float inv = 1.0f / (w0 + w1);
  w0 *= inv; w1 *= inv;
  const size_t o = (size_t)row * DM + col0;
  half8 a = *(const half8*)&AO[o];
  half8 c = *(const half8*)&O1[o];
  half8 r;
#pragma unroll
  for (int i = 0; i < 8; ++i)
    r[i] = (_Float16)(w0 * (float)a[i] + w1 * (float)c[i]);
  *(half8*)&AO[o] = r;
}

extern "C" void kernel_launch(void* const* d_in, const int* in_sizes, int n_in,
                              void* d_out, int out_size, void* d_ws, size_t ws_size,
                              hipStream_t stream) {
  const float* query = (const float*)d_in[0];
  const float* key   = (const float*)d_in[1];
  const float* value = (const float*)d_in[2];
  const float* ck    = (const float*)d_in[3];
  const float* cv    = (const float*)d_in[4];
  const float* wq = (const float*)d_in[5];
  const float* bq = (const float*)d_in[6];
  const float* wk = (const float*)d_in[7];
  const float* bk = (const float*)d_in[8];
  const float* wv = (const float*)d_in[9];
  const float* bv = (const float*)d_in[10];
  const float* wo = (const float*)d_in[11];
  const float* bo = (const float*)d_in[12];

  char* ws = (char*)d_ws;
  _Float16* Kc = (_Float16*)ws;                 // 64 MiB: [4][4096][2048]
  _Float16* Vt = (_Float16*)(ws + 67108864);    // 64 MiB: [4][16][128][4096]
  _Float16* Qp = (_Float16*)(ws + 134217728);   // 8 MiB
  _Float16* AO = (_Float16*)(ws + 142606336);   // 8 MiB

  // input staging (dead regions): qh in AO; kh/vh in d_out (rewritten post-attn)
  _Float16* qh = AO;
  _Float16* kh = (_Float16*)d_out;
  _Float16* vh = (_Float16*)((char*)d_out + 8388608);
  _Float16* woh = Qp;  // converted post-attn

  _Float16* O1s = (_Float16*)d_out;                // 8 MiB
  float2* mls = (float2*)((char*)d_out + 8388608); // 512 KiB

  const long long pb4 = (long long)CL * DM / 4;
  const bool big = ws_size >= (size_t)153 * 1024 * 1024;

  if (big) {
    // weights: wq at ws+144MiB; wk/wv in Kc cache stripes of batches 0/1.
    // convK b2/b3 fused into fused_pre (their stripes are weight-free);
    // b0/b1 convert serially afterwards (weights dead by then).
    _Float16* wqh = (_Float16*)(ws + 150994944);
    _Float16* wkh = Kc;                          // b0 cache stripe
    _Float16* wvh = Kc + (size_t)TT * DM;        // b1 cache stripe
    cvt_f16<<<dim3(512, 6), 256, 0, stream>>>(
        query, key, value, wq, wk, wv, qh, kh, vh, wqh, wkh, wvh);
    fused_pre<<<768 + 3584 + 1024, 512, 0, stream>>>(
        qh, kh, vh, wqh, wkh, wvh, bq, bk, bv, Qp, Kc, Vt, cv, ck);
    convert_Kpart<<<1024, 256, 0, stream>>>(ck, Kc, 0, 2 * pb4);
  } else {
    // R12 layout: weights in Kc stripes; full convK after fused_pre.
    _Float16* wqh = Kc;
    _Float16* wkh = (_Float16*)(ws + 16777216);
    _Float16* wvh = (_Float16*)(ws + 33554432);
    cvt_f16<<<dim3(512, 6), 256, 0, stream>>>(
        query, key, value, wq, wk, wv, qh, kh, vh, wqh, wkh, wvh);
    fused_pre<<<768 + 3584, 512, 0, stream>>>(
        qh, kh, vh, wqh, wkh, wvh, bq, bk, bv, Qp, Kc, Vt, cv, ck);
    convert_Kpart<<<2048, 256, 0, stream>>>(ck, Kc, 0, 4 * pb4);
  }

  attn_kernel<<<256, 512, 0, stream>>>(Qp, Kc, Vt, AO, O1s, mls);
  combine<<<2048, 256, 0, stream>>>(AO, O1s, mls);
  cvt_f16_one<<<512, 256, 0, stream>>>(wo, woh);
  mm16o<<<dim3(16, 16), 512, 0, stream>>>(AO, woh, bo, (float*)d_out);
}

// Round 18
// 313.098 us; speedup vs baseline: 1.1417x; 1.0147x over previous
//
#include <hip/hip_runtime.h>

typedef _Float16 half8 __attribute__((ext_vector_type(8)));
typedef _Float16 half4v __attribute__((ext_vector_type(4)));
typedef float f32x4 __attribute__((ext_vector_type(4)));

#define NB 4
#define SQ 512
#define CL 3584
#define TT 4096
#define DM 2048
#define NH 16
#define DH 128

// XOR swizzles on half-index (attn LDS)
#define KSW(row, col) ((((row) * 128) + (col)) ^ ((((row) & 7) << 3)))
#define VSW(row, col) ((((row) * 64) + (col)) ^ ((((row) & 7) << 3)))
#define PSW(row, col) ((((row) * 64) + (col)) ^ ((((row) & 7) << 3)))

__device__ __forceinline__ void gl_lds16(const void* g, void* l) {
  __builtin_amdgcn_global_load_lds(
      (const __attribute__((address_space(1))) unsigned int*)g,
      (__attribute__((address_space(3))) unsigned int*)l, 16, 0, 0);
}

// ---------------- fp32 -> f16 dense convert, 6 slices in one launch ----------------
__global__ __launch_bounds__(256) void cvt_f16(
    const float* __restrict__ s0, const float* __restrict__ s1, const float* __restrict__ s2,
    const float* __restrict__ s3, const float* __restrict__ s4, const float* __restrict__ s5,
    _Float16* __restrict__ d0, _Float16* __restrict__ d1, _Float16* __restrict__ d2,
    _Float16* __restrict__ d3, _Float16* __restrict__ d4, _Float16* __restrict__ d5)
{
  const int z = blockIdx.y;
  const float* s = z == 0 ? s0 : z == 1 ? s1 : z == 2 ? s2 : z == 3 ? s3 : z == 4 ? s4 : s5;
  _Float16* d = z == 0 ? d0 : z == 1 ? d1 : z == 2 ? d2 : z == 3 ? d3 : z == 4 ? d4 : d5;
  const int n4 = DM * DM / 4;
  for (int v = blockIdx.x * blockDim.x + threadIdx.x; v < n4;
       v += gridDim.x * blockDim.x) {
    float4 x = ((const float4*)s)[v];
    half4v h = { (_Float16)x.x, (_Float16)x.y, (_Float16)x.z, (_Float16)x.w };
    ((half4v*)d)[v] = h;
  }
}

// ---------------- cached K fp32 -> f16 convert over float4 range [v0, v1) ----------------
__global__ __launch_bounds__(256) void convert_Kpart(
    const float* __restrict__ ck, _Float16* __restrict__ K, long long v0, long long v1)
{
  const int pb = CL * DM / 4;
  for (long long v = v0 + (long long)blockIdx.x * blockDim.x + threadIdx.x; v < v1;
       v += (long long)gridDim.x * blockDim.x) {
    int b = (int)(v / pb);
    long long r = v - (long long)b * pb;
    float4 x = ((const float4*)ck)[v];
    half4v hx = { (_Float16)x.x, (_Float16)x.y, (_Float16)x.z, (_Float16)x.w };
    ((half4v*)K)[(long long)b * (TT * DM / 4) + r] = hx;
  }
}

// -- FUSED: QKV GEMM (bid<768) + cached-V transpose (bid<4352) + convK b2/b3 (bid>=4352) --
__global__ __launch_bounds__(512) void fused_pre(
    const _Float16* __restrict__ A0, const _Float16* __restrict__ A1,
    const _Float16* __restrict__ A2,
    const _Float16* __restrict__ W0, const _Float16* __restrict__ W1,
    const _Float16* __restrict__ W2,
    const float* __restrict__ b0, const float* __restrict__ b1,
    const float* __restrict__ b2,
    _Float16* __restrict__ Qp, _Float16* __restrict__ Kc,
    _Float16* __restrict__ Vt, const float* __restrict__ cv,
    const float* __restrict__ ck)
{
  __shared__ __align__(16) char smem[4 * 8192];

  const int bid = blockIdx.x;
  const int tid = threadIdx.x;

  if (bid < 768) {
    char* Abuf = smem;
    char* Wbuf = smem + 2 * 8192;
    const int bm = bid & 15, bn = (bid >> 4) & 15, z = bid >> 8;
    const _Float16* Ain = z == 0 ? A0 : z == 1 ? A1 : A2;
    const _Float16* W   = z == 0 ? W0 : z == 1 ? W1 : W2;
    const float* bias   = z == 0 ? b0 : z == 1 ? b1 : b2;

    const int wid = tid >> 6, lane = tid & 63;
    const int wm = wid >> 2, wn = wid & 3;
    const int lr = lane & 15, lg = lane >> 4;

    f32x4 acc[4][2];
#pragma unroll
    for (int i = 0; i < 4; ++i)
#pragma unroll
      for (int j = 0; j < 2; ++j) acc[i][j] = (f32x4){0.f, 0.f, 0.f, 0.f};

    size_t aoff, woff;
    {
      const int o = wid * 1024 + lane * 16;
      const int prow = o >> 7, pb = o & 127;
      const int lb = pb ^ ((prow & 7) << 4);
      const int r = (prow << 1) | (lb >> 6), c = lb & 63;
      aoff = (size_t)(bm * 128 + r) * 4096 + c;
      woff = (size_t)(bn * 128 + r) * 4096 + c;
    }

    auto stage = [&](int kt, int buf) {
      gl_lds16((const char*)Ain + aoff + kt * 64, Abuf + buf * 8192 + wid * 1024);
      gl_lds16((const char*)W + woff + kt * 64, Wbuf + buf * 8192 + wid * 1024);
    };
    auto lds_addr = [](const char* base, int r, int cb) -> const char* {
      return base + ((r >> 1) << 7) + ((((r & 1) << 6) | cb) ^ (((r >> 1) & 7) << 4));
    };
    auto compute = [&](int buf) {
      const char* ab = Abuf + buf * 8192;
      const char* wb = Wbuf + buf * 8192;
      half8 af[4], bf[2];
#pragma unroll
      for (int i = 0; i < 4; ++i)
        af[i] = *(const half8*)lds_addr(ab, wm * 64 + i * 16 + lr, lg << 4);
#pragma unroll
      for (int j = 0; j < 2; ++j)
        bf[j] = *(const half8*)lds_addr(wb, wn * 32 + j * 16 + lr, lg << 4);
#pragma unroll
      for (int i = 0; i < 4; ++i)
#pragma unroll
        for (int j = 0; j < 2; ++j)
          acc[i][j] = __builtin_amdgcn_mfma_f32_16x16x32_f16(af[i], bf[j], acc[i][j], 0, 0, 0);
    };

    const int NKT = DM / 32;
    stage(0, 0);
    __syncthreads();
    for (int kt = 0; kt < NKT; ++kt) {
      if (kt + 1 < NKT) stage(kt + 1, (kt + 1) & 1);
      compute(kt & 1);
      __syncthreads();
    }

    const float qscale = 0.08838834764831845f * 1.4426950408889634f;
#pragma unroll
    for (int i = 0; i < 4; ++i) {
      const int m0 = bm * 128 + wm * 64 + i * 16 + lg * 4;
#pragma unroll
      for (int j = 0; j < 2; ++j) {
        const int gn = bn * 128 + wn * 32 + j * 16 + lr;
        const float bb = bias[gn];
        if (z == 0) {
#pragma unroll
          for (int r = 0; r < 4; ++r)
            Qp[(size_t)(m0 + r) * DM + gn] = (_Float16)((acc[i][j][r] + bb) * qscale);
        } else if (z == 1) {
          const int b = m0 >> 9;
#pragma unroll
          for (int r = 0; r < 4; ++r)
            Kc[((size_t)b * TT + CL + ((m0 + r) & 511)) * DM + gn] =
                (_Float16)(acc[i][j][r] + bb);
        } else {
          half4v hv;
#pragma unroll
          for (int r = 0; r < 4; ++r) hv[r] = (_Float16)(acc[i][j][r] + bb);
          const int b = m0 >> 9, t = CL + (m0 & 511);
          const int h = gn >> 7, d = gn & 127;
          *(half4v*)&Vt[((size_t)(b * NH + h) * DH + d) * TT + t] = hv;
        }
      }
    }
  } else if (bid < 768 + 3584) {
    // ---------------- cached V transpose: 64t x 128dm tile ----------------
    _Float16 (*T)[136] = (_Float16(*)[136])smem;
    const int tv = bid - 768;
    const int b = tv / 896;
    const int rem = tv - b * 896;
    const int t0 = (rem % 56) * 64;
    const int dm0 = (rem / 56) * 128;
    {
      const int tr = tid >> 3, c0 = (tid & 7) * 16;
      const float* src = cv + ((size_t)b * CL + t0 + tr) * DM + dm0 + c0;
      float4 a0 = ((const float4*)src)[0];
      float4 a1 = ((const float4*)src)[1];
      float4 a2 = ((const float4*)src)[2];
      float4 a3 = ((const float4*)src)[3];
      half8 h0 = { (_Float16)a0.x, (_Float16)a0.y, (_Float16)a0.z, (_Float16)a0.w,
                   (_Float16)a1.x, (_Float16)a1.y, (_Float16)a1.z, (_Float16)a1.w };
      half8 h1 = { (_Float16)a2.x, (_Float16)a2.y, (_Float16)a2.z, (_Float16)a2.w,
                   (_Float16)a3.x, (_Float16)a3.y, (_Float16)a3.z, (_Float16)a3.w };
      *(half8*)&T[tr][c0] = h0;
      *(half8*)&T[tr][c0 + 8] = h1;
    }
    __syncthreads();
    {
      const int dl = tid >> 2, tc = (tid & 3) * 16;
      const int h = dm0 >> 7;
      half8 o0, o1;
#pragma unroll
      for (int i = 0; i < 8; ++i) o0[i] = T[tc + i][dl];
#pragma unroll
      for (int i = 0; i < 8; ++i) o1[i] = T[tc + 8 + i][dl];
      _Float16* dst = Vt + ((size_t)(b * NH + h) * DH + dl) * TT + t0 + tc;
      *(half8*)dst = o0;
      *(half8*)(dst + 8) = o1;
    }
  } else {
    // ---------------- cached K fp32->f16, batches 2..3 (big-ws path only) ----------------
    const int cb = bid - (768 + 3584);
    const int pb = CL * DM / 4;
    const long long nvec = (long long)NB * pb;
    const long long vhalf = 2LL * pb;
    const long long stride = 1024LL * 512;
    for (long long v = vhalf + (long long)cb * 512 + tid; v < nvec; v += stride) {
      int b = (int)(v / pb);
      long long r = v - (long long)b * pb;
      float4 x = ((const float4*)ck)[v];
      half4v hx = { (_Float16)x.x, (_Float16)x.y, (_Float16)x.z, (_Float16)x.w };
      ((half4v*)Kc)[(long long)b * (TT * DM / 4) + r] = hx;
    }
  }
}

// ---------------- O-projection GEMM: 128x64 tiles, grid (16,32), 2+ blocks/CU ----------------
__global__ __launch_bounds__(512) void mm16o(
    const _Float16* __restrict__ Ain, const _Float16* __restrict__ W,
    const float* __restrict__ bias, float* __restrict__ Co)
{
  __shared__ __align__(16) char smem[2 * 8192 + 2 * 4096];
  char* Abuf = smem;                 // 2 x 8KB (128 rows x 64B)
  char* Wbuf = smem + 2 * 8192;      // 2 x 4KB (64 rows x 64B)

  const int tid = threadIdx.x;
  const int bm = blockIdx.x, bn = blockIdx.y;
  const int wid = tid >> 6, lane = tid & 63;
  const int wm = wid >> 1, wn = wid & 1;    // wave tile: rows wm*32, cols wn*32
  const int lr = lane & 15, lg = lane >> 4;

  f32x4 acc[2][2];
#pragma unroll
  for (int i = 0; i < 2; ++i)
#pragma unroll
    for (int j = 0; j < 2; ++j) acc[i][j] = (f32x4){0.f, 0.f, 0.f, 0.f};

  size_t aoff, woff;
  {
    const int o = wid * 1024 + lane * 16;
    const int prow = o >> 7, pb = o & 127;
    const int lb = pb ^ ((prow & 7) << 4);
    const int r = (prow << 1) | (lb >> 6), c = lb & 63;
    aoff = (size_t)(bm * 128 + r) * 4096 + c;   // A rows 0..127
    woff = (size_t)(bn * 64 + r) * 4096 + c;    // W rows 0..63 (wid<4 only)
  }

  auto stage = [&](int kt, int buf) {
    gl_lds16((const char*)Ain + aoff + kt * 64, Abuf + buf * 8192 + wid * 1024);
    if (wid < 4)
      gl_lds16((const char*)W + woff + kt * 64, Wbuf + buf * 4096 + wid * 1024);
  };
  auto lds_addr = [](const char* base, int r, int cb) -> const char* {
    return base + ((r >> 1) << 7) + ((((r & 1) << 6) | cb) ^ (((r >> 1) & 7) << 4));
  };
  auto compute = [&](int buf) {
    const char* ab = Abuf + buf * 8192;
    const char* wb = Wbuf + buf * 4096;
    half8 af[2], bf[2];
#pragma unroll
    for (int i = 0; i < 2; ++i)
      af[i] = *(const half8*)lds_addr(ab, wm * 32 + i * 16 + lr, lg << 4);
#pragma unroll
    for (int j = 0; j < 2; ++j)
      bf[j] = *(const half8*)lds_addr(wb, wn * 32 + j * 16 + lr, lg << 4);
#pragma unroll
    for (int i = 0; i < 2; ++i)
#pragma unroll
      for (int j = 0; j < 2; ++j)
        acc[i][j] = __builtin_amdgcn_mfma_f32_16x16x32_f16(af[i], bf[j], acc[i][j], 0, 0, 0);
  };

  const int NKT = DM / 32;
  stage(0, 0);
  __syncthreads();
  for (int kt = 0; kt < NKT; ++kt) {
    if (kt + 1 < NKT) stage(kt + 1, (kt + 1) & 1);
    compute(kt & 1);
    __syncthreads();
  }

#pragma unroll
  for (int i = 0; i < 2; ++i) {
    const int m0 = bm * 128 + wm * 32 + i * 16 + lg * 4;
#pragma unroll
    for (int j = 0; j < 2; ++j) {
      const int gn = bn * 64 + wn * 32 + j * 16 + lr;
      const float bb = bias[gn];
#pragma unroll
      for (int r = 0; r < 4; ++r)
        Co[(size_t)(m0 + r) * DM + gn] = acc[i][j][r] + bb;
    }
  }
}

// ---------------- flash attention (R12-proven: kv-split x2, pipelined) ----------------
__global__ __launch_bounds__(512) void attn_kernel(
    const _Float16* __restrict__ Qp, const _Float16* __restrict__ Kc,
    const _Float16* __restrict__ Vt, _Float16* __restrict__ O0,
    _Float16* __restrict__ O1, float2* __restrict__ ml)
{
  __shared__ _Float16 Ks[2][64 * 128];
  __shared__ _Float16 VTs[3][128 * 64];
  __shared__ _Float16 Ps[8][32 * 64];

  const int tid = threadIdx.x;
  const int lin = blockIdx.x;
  const int xcd = lin & 7, slot = lin >> 3;
  const int pair = xcd * 8 + (slot >> 2);
  const int rem = slot & 3;
  const int qb = rem >> 1, part = rem & 1;
  const int b = pair >> 4, h = pair & 15;

  const int wid = tid >> 6, lane = tid & 63;
  const int lr = lane & 15, lg = lane >> 4;
  const int qw = qb * 256 + wid * 32;

  half8 qf[2][4];
#pragma unroll
  for (int qs = 0; qs < 2; ++qs)
#pragma unroll
    for (int kk = 0; kk < 4; ++kk)
      qf[qs][kk] = *(const half8*)&Qp[(size_t)(b * SQ + qw + qs * 16 + lr) * DM +
                                      h * DH + kk * 32 + lg * 8];

  f32x4 zero = {0.f, 0.f, 0.f, 0.f};
  f32x4 acc[8][2];
#pragma unroll
  for (int d = 0; d < 8; ++d)
#pragma unroll
    for (int qs = 0; qs < 2; ++qs) acc[d][qs] = zero;
  float m_run[2] = {-1e30f, -1e30f}, l_run[2] = {0.f, 0.f};

  const int nt_full = (CL + qb * 256 + 256) / 64;
  const int halfn = nt_full >> 1;
  const int tbeg = part ? halfn : 0;
  const int nt = part ? (nt_full - halfn) : halfn;

  int ksrc[2], vsrc[2];
#pragma unroll
  for (int c = 0; c < 2; ++c) {
    const int p = c * 512 + wid * 64 + lane;
    { const int r = p >> 4, pg = p & 15, gc = pg ^ (r & 7);
      ksrc[c] = r * DM + gc * 8; }
    { const int d = p >> 3, pg = p & 7, gt = pg ^ (d & 7);
      vsrc[c] = d * TT + gt * 8; }
  }
  const _Float16* Kb = Kc + (size_t)b * TT * DM + h * DH;
  const _Float16* Vb = Vt + (size_t)(b * NH + h) * DH * TT;

  auto stage = [&](int tt, int kbuf, int vbuf) {
    const int t0 = (tbeg + tt) * 64;
#pragma unroll
    for (int c = 0; c < 2; ++c)
      gl_lds16(Kb + (size_t)t0 * DM + ksrc[c], &Ks[kbuf][(c * 512 + wid * 64) * 8]);
#pragma unroll
    for (int c = 0; c < 2; ++c)
      gl_lds16(Vb + t0 + vsrc[c], &VTs[vbuf][(c * 512 + wid * 64) * 8]);
  };

  auto qk = [&](int kbuf, f32x4 (*s)[2]) {
#pragma unroll
    for (int j = 0; j < 4; ++j)
#pragma unroll
      for (int qs = 0; qs < 2; ++qs) s[j][qs] = zero;
#pragma unroll
    for (int kk = 0; kk < 4; ++kk)
#pragma unroll
      for (int j = 0; j < 4; ++j) {
        half8 kb = *(const half8*)&Ks[kbuf][KSW(j * 16 + lr, kk * 32 + lg * 8)];
        s[j][0] = __builtin_amdgcn_mfma_f32_16x16x32_f16(kb, qf[0][kk], s[j][0], 0, 0, 0);
        s[j][1] = __builtin_amdgcn_mfma_f32_16x16x32_f16(kb, qf[1][kk], s[j][1], 0, 0, 0);
      }
  };

  auto mask_s = [&](int t0, f32x4 (*s)[2]) {
    if (part && t0 + 63 > CL + qw) {
#pragma unroll
      for (int j = 0; j < 4; ++j)
#pragma unroll
        for (int qs = 0; qs < 2; ++qs)
#pragma unroll
          for (int r = 0; r < 4; ++r)
            if (t0 + j * 16 + lg * 4 + r > CL + qw + qs * 16 + lr) s[j][qs][r] = -1e30f;
    }
  };

  auto softmax_step = [&](f32x4 (*s)[2]) {
    float mt[2];
#pragma unroll
    for (int qs = 0; qs < 2; ++qs) {
      float m = s[0][qs][0];
#pragma unroll
      for (int j = 0; j < 4; ++j)
#pragma unroll
        for (int r = 0; r < 4; ++r) m = fmaxf(m, s[j][qs][r]);
      mt[qs] = m;
    }
    if (!__all(mt[0] <= m_run[0] + 10.0f && mt[1] <= m_run[1] + 10.0f)) {
#pragma unroll
      for (int qs = 0; qs < 2; ++qs) {
        float m = fmaxf(mt[qs], __shfl_xor(mt[qs], 16));
        m = fmaxf(m, __shfl_xor(m, 32));
        const float mn = fmaxf(m_run[qs], m);
        const float fsc = exp2f(m_run[qs] - mn);
        m_run[qs] = mn;
        l_run[qs] *= fsc;
#pragma unroll
        for (int d = 0; d < 8; ++d)
#pragma unroll
          for (int r = 0; r < 4; ++r) acc[d][qs][r] *= fsc;
      }
    }
#pragma unroll
    for (int qs = 0; qs < 2; ++qs) {
      float ps = 0.f;
#pragma unroll
      for (int j = 0; j < 4; ++j) {
        float p0 = exp2f(s[j][qs][0] - m_run[qs]);
        float p1 = exp2f(s[j][qs][1] - m_run[qs]);
        float p2 = exp2f(s[j][qs][2] - m_run[qs]);
        float p3 = exp2f(s[j][qs][3] - m_run[qs]);
        ps += (p0 + p1) + (p2 + p3);
        half4v hp = { (_Float16)p0, (_Float16)p1, (_Float16)p2, (_Float16)p3 };
        *(half4v*)&Ps[wid][PSW(qs * 16 + lr, j * 16 + lg * 4)] = hp;
      }
      l_run[qs] += ps;
    }
  };

  auto pv = [&](int vbuf) {
#pragma unroll
    for (int kk = 0; kk < 2; ++kk) {
      half8 pf0 = *(const half8*)&Ps[wid][PSW(lr, kk * 32 + lg * 8)];
      half8 pf1 = *(const half8*)&Ps[wid][PSW(16 + lr, kk * 32 + lg * 8)];
#pragma unroll
      for (int d = 0; d < 8; ++d) {
        half8 vf = *(const half8*)&VTs[vbuf][VSW(d * 16 + lr, kk * 32 + lg * 8)];
        acc[d][0] = __builtin_amdgcn_mfma_f32_16x16x32_f16(vf, pf0, acc[d][0], 0, 0, 0);
        acc[d][1] = __builtin_amdgcn_mfma_f32_16x16x32_f16(vf, pf1, acc[d][1], 0, 0, 0);
      }
    }
  };

  f32x4 sp[4][2], sc[4][2];

  stage(0, 0, 0);
  __syncthreads();
  stage(1, 1, 1);
  qk(0, sp);
  mask_s(tbeg * 64, sp);

  for (int t = 1; t < nt; ++t) {
    __syncthreads();
    if (t + 1 < nt) stage(t + 1, (t + 1) & 1, (t + 1) % 3);
    qk(t & 1, sc);
    softmax_step(sp);
    pv((t - 1) % 3);
    mask_s((tbeg + t) * 64, sc);
#pragma unroll
    for (int j = 0; j < 4; ++j)
#pragma unroll
      for (int qs = 0; qs < 2; ++qs) sp[j][qs] = sc[j][qs];
  }
  softmax_step(sp);
  pv((nt - 1) % 3);

  _Float16* Od = part ? O1 : O0;
#pragma unroll
  for (int qs = 0; qs < 2; ++qs) {
    float lt = l_run[qs] + __shfl_xor(l_run[qs], 16);
    lt += __shfl_xor(lt, 32);
    const float inv = 1.0f / lt;
#pragma unroll
    for (int d = 0; d < 8; ++d) {
      half4v hv;
#pragma unroll
      for (int r = 0; r < 4; ++r) hv[r] = (_Float16)(acc[d][qs][r] * inv);
      *(half4v*)&Od[(size_t)(b * SQ + qw + qs * 16 + lr) * DM + h * DH + d * 16 + lg * 4] = hv;
    }
    if (lg == 0) {
      float2 e; e.x = m_run[qs]; e.y = lt;
      ml[part * (64 * SQ) + ((b * NH + h) * SQ) + qw + qs * 16 + lr] = e;
    }
  }
}

// ---------------- combine partitions (bid<2048) + wo fp32->f16 (bid>=2048) ----------------
__global__ __launch_bounds__(256) void combine_cvt(
    _Float16* __restrict__ AO, const _Float16* __restrict__ O1,
    const float2* __restrict__ ml,
    const float* __restrict__ wo, _Float16* __restrict__ woh)
{
  const int bid = blockIdx.x;
  if (bid < 2048) {
    const int idx = bid * 256 + threadIdx.x;
    const int row = idx >> 8;
    const int col0 = (idx & 255) * 8;
    const int b = row >> 9, q = row & 511, h = col0 >> 7;
    const float2 e0 = ml[(b * NH + h) * SQ + q];
    const float2 e1 = ml[64 * SQ + (b * NH + h) * SQ + q];
    const float m = fmaxf(e0.x, e1.x);
    float w0 = e0.y * exp2f(e0.x - m);
    float w1 = e1.y * exp2f(e1.x - m);
    const float inv = 1.0f / (w0 + w1);
    w0 *= inv; w1 *= inv;
    const size_t o = (size_t)row * DM + col0;
    half8 a = *(const half8*)&AO[o];
    half8 c = *(const half8*)&O1[o];
    half8 r;
#pragma unroll
    for (int i = 0; i < 8; ++i)
      r[i] = (_Float16)(w0 * (float)a[i] + w1 * (float)c[i]);
    *(half8*)&AO[o] = r;
  } else {
    const int cb = bid - 2048;                // 0..511
    const int n4 = DM * DM / 4;
    for (int v = cb * 256 + threadIdx.x; v < n4; v += 512 * 256) {
      float4 x = ((const float4*)wo)[v];
      half4v h = { (_Float16)x.x, (_Float16)x.y, (_Float16)x.z, (_Float16)x.w };
      ((half4v*)woh)[v] = h;
    }
  }
}

extern "C" void kernel_launch(void* const* d_in, const int* in_sizes, int n_in,
                              void* d_out, int out_size, void* d_ws, size_t ws_size,
                              hipStream_t stream) {
  const float* query = (const float*)d_in[0];
  const float* key   = (const float*)d_in[1];
  const float* value = (const float*)d_in[2];
  const float* ck    = (const float*)d_in[3];
  const float* cv    = (const float*)d_in[4];
  const float* wq = (const float*)d_in[5];
  const float* bq = (const float*)d_in[6];
  const float* wk = (const float*)d_in[7];
  const float* bk = (const float*)d_in[8];
  const float* wv = (const float*)d_in[9];
  const float* bv = (const float*)d_in[10];
  const float* wo = (const float*)d_in[11];
  const float* bo = (const float*)d_in[12];

  char* ws = (char*)d_ws;
  _Float16* Kc = (_Float16*)ws;                 // 64 MiB: [4][4096][2048]
  _Float16* Vt = (_Float16*)(ws + 67108864);    // 64 MiB: [4][16][128][4096]
  _Float16* Qp = (_Float16*)(ws + 134217728);   // 8 MiB
  _Float16* AO = (_Float16*)(ws + 142606336);   // 8 MiB

  _Float16* qh = AO;
  _Float16* kh = (_Float16*)d_out;
  _Float16* vh = (_Float16*)((char*)d_out + 8388608);
  _Float16* woh = Qp;  // converted post-attn (Qp dead after attn)

  _Float16* O1s = (_Float16*)d_out;                // 8 MiB
  float2* mls = (float2*)((char*)d_out + 8388608); // 512 KiB

  const long long pb4 = (long long)CL * DM / 4;
  const bool big = ws_size >= (size_t)153 * 1024 * 1024;

  if (big) {
    _Float16* wqh = (_Float16*)(ws + 150994944);
    _Float16* wkh = Kc;                          // b0 cache stripe
    _Float16* wvh = Kc + (size_t)TT * DM;        // b1 cache stripe
    cvt_f16<<<dim3(512, 6), 256, 0, stream>>>(
        query, key, value, wq, wk, wv, qh, kh, vh, wqh, wkh, wvh);
    fused_pre<<<768 + 3584 + 1024, 512, 0, stream>>>(
        qh, kh, vh, wqh, wkh, wvh, bq, bk, bv, Qp, Kc, Vt, cv, ck);
    convert_Kpart<<<1024, 256, 0, stream>>>(ck, Kc, 0, 2 * pb4);
  } else {
    _Float16* wqh = Kc;
    _Float16* wkh = (_Float16*)(ws + 16777216);
    _Float16* wvh = (_Float16*)(ws + 33554432);
    cvt_f16<<<dim3(512, 6), 256, 0, stream>>>(
        query, key, value, wq, wk, wv, qh, kh, vh, wqh, wkh, wvh);
    fused_pre<<<768 + 3584, 512, 0, stream>>>(
        qh, kh, vh, wqh, wkh, wvh, bq, bk, bv, Qp, Kc, Vt, cv, ck);
    convert_Kpart<<<2048, 256, 0, stream>>>(ck, Kc, 0, 4 * pb4);
  }

  attn_kernel<<<256, 512, 0, stream>>>(Qp, Kc, Vt, AO, O1s, mls);
  combine_cvt<<<2048 + 512, 256, 0, stream>>>(AO, O1s, mls, wo, woh);
  mm16o<<<dim3(16, 32), 512, 0, stream>>>(AO, woh, bo, (float*)d_out);
}

// Round 19
// 306.989 us; speedup vs baseline: 1.1644x; 1.0199x over previous
//
#include <hip/hip_runtime.h>

typedef _Float16 half8 __attribute__((ext_vector_type(8)));
typedef _Float16 half4v __attribute__((ext_vector_type(4)));
typedef float f32x4 __attribute__((ext_vector_type(4)));

#define NB 4
#define SQ 512
#define CL 3584
#define TT 4096
#define DM 2048
#define NH 16
#define DH 128

// XOR swizzles on half-index (attn LDS)
#define KSW(row, col) ((((row) * 128) + (col)) ^ ((((row) & 7) << 3)))
#define VSW(row, col) ((((row) * 64) + (col)) ^ ((((row) & 7) << 3)))
#define PSW(row, col) ((((row) * 64) + (col)) ^ ((((row) & 7) << 3)))

__device__ __forceinline__ void gl_lds16(const void* g, void* l) {
  __builtin_amdgcn_global_load_lds(
      (const __attribute__((address_space(1))) unsigned int*)g,
      (__attribute__((address_space(3))) unsigned int*)l, 16, 0, 0);
}

// ---------------- fp32 -> f16 dense convert, 6 slices in one launch ----------------
__global__ __launch_bounds__(256) void cvt_f16(
    const float* __restrict__ s0, const float* __restrict__ s1, const float* __restrict__ s2,
    const float* __restrict__ s3, const float* __restrict__ s4, const float* __restrict__ s5,
    _Float16* __restrict__ d0, _Float16* __restrict__ d1, _Float16* __restrict__ d2,
    _Float16* __restrict__ d3, _Float16* __restrict__ d4, _Float16* __restrict__ d5)
{
  const int z = blockIdx.y;
  const float* s = z == 0 ? s0 : z == 1 ? s1 : z == 2 ? s2 : z == 3 ? s3 : z == 4 ? s4 : s5;
  _Float16* d = z == 0 ? d0 : z == 1 ? d1 : z == 2 ? d2 : z == 3 ? d3 : z == 4 ? d4 : d5;
  const int n4 = DM * DM / 4;
  for (int v = blockIdx.x * blockDim.x + threadIdx.x; v < n4;
       v += gridDim.x * blockDim.x) {
    float4 x = ((const float4*)s)[v];
    half4v h = { (_Float16)x.x, (_Float16)x.y, (_Float16)x.z, (_Float16)x.w };
    ((half4v*)d)[v] = h;
  }
}

// ---------------- cached K fp32 -> f16 convert over float4 range [v0, v1) ----------------
__global__ __launch_bounds__(256) void convert_Kpart(
    const float* __restrict__ ck, _Float16* __restrict__ K, long long v0, long long v1)
{
  const int pb = CL * DM / 4;
  for (long long v = v0 + (long long)blockIdx.x * blockDim.x + threadIdx.x; v < v1;
       v += (long long)gridDim.x * blockDim.x) {
    int b = (int)(v / pb);
    long long r = v - (long long)b * pb;
    float4 x = ((const float4*)ck)[v];
    half4v hx = { (_Float16)x.x, (_Float16)x.y, (_Float16)x.z, (_Float16)x.w };
    ((half4v*)K)[(long long)b * (TT * DM / 4) + r] = hx;
  }
}

// -- FUSED: QKV GEMM (bid<768) + cached-V transpose (bid<4352) + convK [cvstart..] (rest) --
__global__ __launch_bounds__(512) void fused_pre(
    const _Float16* __restrict__ A0, const _Float16* __restrict__ A1,
    const _Float16* __restrict__ A2,
    const _Float16* __restrict__ W0, const _Float16* __restrict__ W1,
    const _Float16* __restrict__ W2,
    const float* __restrict__ b0, const float* __restrict__ b1,
    const float* __restrict__ b2,
    _Float16* __restrict__ Qp, _Float16* __restrict__ Kc,
    _Float16* __restrict__ Vt, const float* __restrict__ cv,
    const float* __restrict__ ck, long long cvstart)
{
  __shared__ __align__(16) char smem[4 * 8192];

  const int bid = blockIdx.x;
  const int tid = threadIdx.x;

  if (bid < 768) {
    char* Abuf = smem;
    char* Wbuf = smem + 2 * 8192;
    const int bm = bid & 15, bn = (bid >> 4) & 15, z = bid >> 8;
    const _Float16* Ain = z == 0 ? A0 : z == 1 ? A1 : A2;
    const _Float16* W   = z == 0 ? W0 : z == 1 ? W1 : W2;
    const float* bias   = z == 0 ? b0 : z == 1 ? b1 : b2;

    const int wid = tid >> 6, lane = tid & 63;
    const int wm = wid >> 2, wn = wid & 3;
    const int lr = lane & 15, lg = lane >> 4;

    f32x4 acc[4][2];
#pragma unroll
    for (int i = 0; i < 4; ++i)
#pragma unroll
      for (int j = 0; j < 2; ++j) acc[i][j] = (f32x4){0.f, 0.f, 0.f, 0.f};

    size_t aoff, woff;
    {
      const int o = wid * 1024 + lane * 16;
      const int prow = o >> 7, pb = o & 127;
      const int lb = pb ^ ((prow & 7) << 4);
      const int r = (prow << 1) | (lb >> 6), c = lb & 63;
      aoff = (size_t)(bm * 128 + r) * 4096 + c;
      woff = (size_t)(bn * 128 + r) * 4096 + c;
    }

    auto stage = [&](int kt, int buf) {
      gl_lds16((const char*)Ain + aoff + kt * 64, Abuf + buf * 8192 + wid * 1024);
      gl_lds16((const char*)W + woff + kt * 64, Wbuf + buf * 8192 + wid * 1024);
    };
    auto lds_addr = [](const char* base, int r, int cb) -> const char* {
      return base + ((r >> 1) << 7) + ((((r & 1) << 6) | cb) ^ (((r >> 1) & 7) << 4));
    };
    auto compute = [&](int buf) {
      const char* ab = Abuf + buf * 8192;
      const char* wb = Wbuf + buf * 8192;
      half8 af[4], bf[2];
#pragma unroll
      for (int i = 0; i < 4; ++i)
        af[i] = *(const half8*)lds_addr(ab, wm * 64 + i * 16 + lr, lg << 4);
#pragma unroll
      for (int j = 0; j < 2; ++j)
        bf[j] = *(const half8*)lds_addr(wb, wn * 32 + j * 16 + lr, lg << 4);
#pragma unroll
      for (int i = 0; i < 4; ++i)
#pragma unroll
        for (int j = 0; j < 2; ++j)
          acc[i][j] = __builtin_amdgcn_mfma_f32_16x16x32_f16(af[i], bf[j], acc[i][j], 0, 0, 0);
    };

    const int NKT = DM / 32;
    stage(0, 0);
    __syncthreads();
    for (int kt = 0; kt < NKT; ++kt) {
      if (kt + 1 < NKT) stage(kt + 1, (kt + 1) & 1);
      compute(kt & 1);
      __syncthreads();
    }

    const float qscale = 0.08838834764831845f * 1.4426950408889634f;
#pragma unroll
    for (int i = 0; i < 4; ++i) {
      const int m0 = bm * 128 + wm * 64 + i * 16 + lg * 4;
#pragma unroll
      for (int j = 0; j < 2; ++j) {
        const int gn = bn * 128 + wn * 32 + j * 16 + lr;
        const float bb = bias[gn];
        if (z == 0) {
#pragma unroll
          for (int r = 0; r < 4; ++r)
            Qp[(size_t)(m0 + r) * DM + gn] = (_Float16)((acc[i][j][r] + bb) * qscale);
        } else if (z == 1) {
          const int b = m0 >> 9;
#pragma unroll
          for (int r = 0; r < 4; ++r)
            Kc[((size_t)b * TT + CL + ((m0 + r) & 511)) * DM + gn] =
                (_Float16)(acc[i][j][r] + bb);
        } else {
          half4v hv;
#pragma unroll
          for (int r = 0; r < 4; ++r) hv[r] = (_Float16)(acc[i][j][r] + bb);
          const int b = m0 >> 9, t = CL + (m0 & 511);
          const int h = gn >> 7, d = gn & 127;
          *(half4v*)&Vt[((size_t)(b * NH + h) * DH + d) * TT + t] = hv;
        }
      }
    }
  } else if (bid < 768 + 3584) {
    // ---------------- cached V transpose: 64t x 128dm tile ----------------
    _Float16 (*T)[136] = (_Float16(*)[136])smem;
    const int tv = bid - 768;
    const int b = tv / 896;
    const int rem = tv - b * 896;
    const int t0 = (rem % 56) * 64;
    const int dm0 = (rem / 56) * 128;
    {
      const int tr = tid >> 3, c0 = (tid & 7) * 16;
      const float* src = cv + ((size_t)b * CL + t0 + tr) * DM + dm0 + c0;
      float4 a0 = ((const float4*)src)[0];
      float4 a1 = ((const float4*)src)[1];
      float4 a2 = ((const float4*)src)[2];
      float4 a3 = ((const float4*)src)[3];
      half8 h0 = { (_Float16)a0.x, (_Float16)a0.y, (_Float16)a0.z, (_Float16)a0.w,
                   (_Float16)a1.x, (_Float16)a1.y, (_Float16)a1.z, (_Float16)a1.w };
      half8 h1 = { (_Float16)a2.x, (_Float16)a2.y, (_Float16)a2.z, (_Float16)a2.w,
                   (_Float16)a3.x, (_Float16)a3.y, (_Float16)a3.z, (_Float16)a3.w };
      *(half8*)&T[tr][c0] = h0;
      *(half8*)&T[tr][c0 + 8] = h1;
    }
    __syncthreads();
    {
      const int dl = tid >> 2, tc = (tid & 3) * 16;
      const int h = dm0 >> 7;
      half8 o0, o1;
#pragma unroll
      for (int i = 0; i < 8; ++i) o0[i] = T[tc + i][dl];
#pragma unroll
      for (int i = 0; i < 8; ++i) o1[i] = T[tc + 8 + i][dl];
      _Float16* dst = Vt + ((size_t)(b * NH + h) * DH + dl) * TT + t0 + tc;
      *(half8*)dst = o0;
      *(half8*)(dst + 8) = o1;
    }
  } else {
    // ---------------- cached K fp32->f16 over [cvstart, nvec) ----------------
    const int cb = bid - (768 + 3584);
    const int ncb = gridDim.x - (768 + 3584);
    const int pb = CL * DM / 4;
    const long long nvec = (long long)NB * pb;
    const long long stride = (long long)ncb * 512;
    for (long long v = cvstart + (long long)cb * 512 + tid; v < nvec; v += stride) {
      int b = (int)(v / pb);
      long long r = v - (long long)b * pb;
      float4 x = ((const float4*)ck)[v];
      half4v hx = { (_Float16)x.x, (_Float16)x.y, (_Float16)x.z, (_Float16)x.w };
      ((half4v*)Kc)[(long long)b * (TT * DM / 4) + r] = hx;
    }
  }
}

// ---------------- O-projection GEMM: 128x64 tiles, grid (16,32) ----------------
__global__ __launch_bounds__(512) void mm16o(
    const _Float16* __restrict__ Ain, const _Float16* __restrict__ W,
    const float* __restrict__ bias, float* __restrict__ Co)
{
  __shared__ __align__(16) char smem[2 * 8192 + 2 * 4096];
  char* Abuf = smem;
  char* Wbuf = smem + 2 * 8192;

  const int tid = threadIdx.x;
  const int bm = blockIdx.x, bn = blockIdx.y;
  const int wid = tid >> 6, lane = tid & 63;
  const int wm = wid >> 1, wn = wid & 1;
  const int lr = lane & 15, lg = lane >> 4;

  f32x4 acc[2][2];
#pragma unroll
  for (int i = 0; i < 2; ++i)
#pragma unroll
    for (int j = 0; j < 2; ++j) acc[i][j] = (f32x4){0.f, 0.f, 0.f, 0.f};

  size_t aoff, woff;
  {
    const int o = wid * 1024 + lane * 16;
    const int prow = o >> 7, pb = o & 127;
    const int lb = pb ^ ((prow & 7) << 4);
    const int r = (prow << 1) | (lb >> 6), c = lb & 63;
    aoff = (size_t)(bm * 128 + r) * 4096 + c;
    woff = (size_t)(bn * 64 + r) * 4096 + c;
  }

  auto stage = [&](int kt, int buf) {
    gl_lds16((const char*)Ain + aoff + kt * 64, Abuf + buf * 8192 + wid * 1024);
    if (wid < 4)
      gl_lds16((const char*)W + woff + kt * 64, Wbuf + buf * 4096 + wid * 1024);
  };
  auto lds_addr = [](const char* base, int r, int cb) -> const char* {
    return base + ((r >> 1) << 7) + ((((r & 1) << 6) | cb) ^ (((r >> 1) & 7) << 4));
  };
  auto compute = [&](int buf) {
    const char* ab = Abuf + buf * 8192;
    const char* wb = Wbuf + buf * 4096;
    half8 af[2], bf[2];
#pragma unroll
    for (int i = 0; i < 2; ++i)
      af[i] = *(const half8*)lds_addr(ab, wm * 32 + i * 16 + lr, lg << 4);
#pragma unroll
    for (int j = 0; j < 2; ++j)
      bf[j] = *(const half8*)lds_addr(wb, wn * 32 + j * 16 + lr, lg << 4);
#pragma unroll
    for (int i = 0; i < 2; ++i)
#pragma unroll
      for (int j = 0; j < 2; ++j)
        acc[i][j] = __builtin_amdgcn_mfma_f32_16x16x32_f16(af[i], bf[j], acc[i][j], 0, 0, 0);
  };

  const int NKT = DM / 32;
  stage(0, 0);
  __syncthreads();
  for (int kt = 0; kt < NKT; ++kt) {
    if (kt + 1 < NKT) stage(kt + 1, (kt + 1) & 1);
    compute(kt & 1);
    __syncthreads();
  }

#pragma unroll
  for (int i = 0; i < 2; ++i) {
    const int m0 = bm * 128 + wm * 32 + i * 16 + lg * 4;
#pragma unroll
    for (int j = 0; j < 2; ++j) {
      const int gn = bn * 64 + wn * 32 + j * 16 + lr;
      const float bb = bias[gn];
#pragma unroll
      for (int r = 0; r < 4; ++r)
        Co[(size_t)(m0 + r) * DM + gn] = acc[i][j][r] + bb;
    }
  }
}

// ---------------- flash attention (R12-proven: kv-split x2, pipelined) ----------------
__global__ __launch_bounds__(512) void attn_kernel(
    const _Float16* __restrict__ Qp, const _Float16* __restrict__ Kc,
    const _Float16* __restrict__ Vt, _Float16* __restrict__ O0,
    _Float16* __restrict__ O1, float2* __restrict__ ml)
{
  __shared__ _Float16 Ks[2][64 * 128];
  __shared__ _Float16 VTs[3][128 * 64];
  __shared__ _Float16 Ps[8][32 * 64];

  const int tid = threadIdx.x;
  const int lin = blockIdx.x;
  const int xcd = lin & 7, slot = lin >> 3;
  const int pair = xcd * 8 + (slot >> 2);
  const int rem = slot & 3;
  const int qb = rem >> 1, part = rem & 1;
  const int b = pair >> 4, h = pair & 15;

  const int wid = tid >> 6, lane = tid & 63;
  const int lr = lane & 15, lg = lane >> 4;
  const int qw = qb * 256 + wid * 32;

  half8 qf[2][4];
#pragma unroll
  for (int qs = 0; qs < 2; ++qs)
#pragma unroll
    for (int kk = 0; kk < 4; ++kk)
      qf[qs][kk] = *(const half8*)&Qp[(size_t)(b * SQ + qw + qs * 16 + lr) * DM +
                                      h * DH + kk * 32 + lg * 8];

  f32x4 zero = {0.f, 0.f, 0.f, 0.f};
  f32x4 acc[8][2];
#pragma unroll
  for (int d = 0; d < 8; ++d)
#pragma unroll
    for (int qs = 0; qs < 2; ++qs) acc[d][qs] = zero;
  float m_run[2] = {-1e30f, -1e30f}, l_run[2] = {0.f, 0.f};

  const int nt_full = (CL + qb * 256 + 256) / 64;
  const int halfn = nt_full >> 1;
  const int tbeg = part ? halfn : 0;
  const int nt = part ? (nt_full - halfn) : halfn;

  int ksrc[2], vsrc[2];
#pragma unroll
  for (int c = 0; c < 2; ++c) {
    const int p = c * 512 + wid * 64 + lane;
    { const int r = p >> 4, pg = p & 15, gc = pg ^ (r & 7);
      ksrc[c] = r * DM + gc * 8; }
    { const int d = p >> 3, pg = p & 7, gt = pg ^ (d & 7);
      vsrc[c] = d * TT + gt * 8; }
  }
  const _Float16* Kb = Kc + (size_t)b * TT * DM + h * DH;
  const _Float16* Vb = Vt + (size_t)(b * NH + h) * DH * TT;

  auto stage = [&](int tt, int kbuf, int vbuf) {
    const int t0 = (tbeg + tt) * 64;
#pragma unroll
    for (int c = 0; c < 2; ++c)
      gl_lds16(Kb + (size_t)t0 * DM + ksrc[c], &Ks[kbuf][(c * 512 + wid * 64) * 8]);
#pragma unroll
    for (int c = 0; c < 2; ++c)
      gl_lds16(Vb + t0 + vsrc[c], &VTs[vbuf][(c * 512 + wid * 64) * 8]);
  };

  auto qk = [&](int kbuf, f32x4 (*s)[2]) {
#pragma unroll
    for (int j = 0; j < 4; ++j)
#pragma unroll
      for (int qs = 0; qs < 2; ++qs) s[j][qs] = zero;
#pragma unroll
    for (int kk = 0; kk < 4; ++kk)
#pragma unroll
      for (int j = 0; j < 4; ++j) {
        half8 kb = *(const half8*)&Ks[kbuf][KSW(j * 16 + lr, kk * 32 + lg * 8)];
        s[j][0] = __builtin_amdgcn_mfma_f32_16x16x32_f16(kb, qf[0][kk], s[j][0], 0, 0, 0);
        s[j][1] = __builtin_amdgcn_mfma_f32_16x16x32_f16(kb, qf[1][kk], s[j][1], 0, 0, 0);
      }
  };

  auto mask_s = [&](int t0, f32x4 (*s)[2]) {
    if (part && t0 + 63 > CL + qw) {
#pragma unroll
      for (int j = 0; j < 4; ++j)
#pragma unroll
        for (int qs = 0; qs < 2; ++qs)
#pragma unroll
          for (int r = 0; r < 4; ++r)
            if (t0 + j * 16 + lg * 4 + r > CL + qw + qs * 16 + lr) s[j][qs][r] = -1e30f;
    }
  };

  auto softmax_step = [&](f32x4 (*s)[2]) {
    float mt[2];
#pragma unroll
    for (int qs = 0; qs < 2; ++qs) {
      float m = s[0][qs][0];
#pragma unroll
      for (int j = 0; j < 4; ++j)
#pragma unroll
        for (int r = 0; r < 4; ++r) m = fmaxf(m, s[j][qs][r]);
      mt[qs] = m;
    }
    if (!__all(mt[0] <= m_run[0] + 10.0f && mt[1] <= m_run[1] + 10.0f)) {
#pragma unroll
      for (int qs = 0; qs < 2; ++qs) {
        float m = fmaxf(mt[qs], __shfl_xor(mt[qs], 16));
        m = fmaxf(m, __shfl_xor(m, 32));
        const float mn = fmaxf(m_run[qs], m);
        const float fsc = exp2f(m_run[qs] - mn);
        m_run[qs] = mn;
        l_run[qs] *= fsc;
#pragma unroll
        for (int d = 0; d < 8; ++d)
#pragma unroll
          for (int r = 0; r < 4; ++r) acc[d][qs][r] *= fsc;
      }
    }
#pragma unroll
    for (int qs = 0; qs < 2; ++qs) {
      float ps = 0.f;
#pragma unroll
      for (int j = 0; j < 4; ++j) {
        float p0 = exp2f(s[j][qs][0] - m_run[qs]);
        float p1 = exp2f(s[j][qs][1] - m_run[qs]);
        float p2 = exp2f(s[j][qs][2] - m_run[qs]);
        float p3 = exp2f(s[j][qs][3] - m_run[qs]);
        ps += (p0 + p1) + (p2 + p3);
        half4v hp = { (_Float16)p0, (_Float16)p1, (_Float16)p2, (_Float16)p3 };
        *(half4v*)&Ps[wid][PSW(qs * 16 + lr, j * 16 + lg * 4)] = hp;
      }
      l_run[qs] += ps;
    }
  };

  auto pv = [&](int vbuf) {
#pragma unroll
    for (int kk = 0; kk < 2; ++kk) {
      half8 pf0 = *(const half8*)&Ps[wid][PSW(lr, kk * 32 + lg * 8)];
      half8 pf1 = *(const half8*)&Ps[wid][PSW(16 + lr, kk * 32 + lg * 8)];
#pragma unroll
      for (int d = 0; d < 8; ++d) {
        half8 vf = *(const half8*)&VTs[vbuf][VSW(d * 16 + lr, kk * 32 + lg * 8)];
        acc[d][0] = __builtin_amdgcn_mfma_f32_16x16x32_f16(vf, pf0, acc[d][0], 0, 0, 0);
        acc[d][1] = __builtin_amdgcn_mfma_f32_16x16x32_f16(vf, pf1, acc[d][1], 0, 0, 0);
      }
    }
  };

  f32x4 sp[4][2], sc[4][2];

  stage(0, 0, 0);
  __syncthreads();
  stage(1, 1, 1);
  qk(0, sp);
  mask_s(tbeg * 64, sp);

  for (int t = 1; t < nt; ++t) {
    __syncthreads();
    if (t + 1 < nt) stage(t + 1, (t + 1) & 1, (t + 1) % 3);
    qk(t & 1, sc);
    softmax_step(sp);
    pv((t - 1) % 3);
    mask_s((tbeg + t) * 64, sc);
#pragma unroll
    for (int j = 0; j < 4; ++j)
#pragma unroll
      for (int qs = 0; qs < 2; ++qs) sp[j][qs] = sc[j][qs];
  }
  softmax_step(sp);
  pv((nt - 1) % 3);

  _Float16* Od = part ? O1 : O0;
#pragma unroll
  for (int qs = 0; qs < 2; ++qs) {
    float lt = l_run[qs] + __shfl_xor(l_run[qs], 16);
    lt += __shfl_xor(lt, 32);
    const float inv = 1.0f / lt;
#pragma unroll
    for (int d = 0; d < 8; ++d) {
      half4v hv;
#pragma unroll
      for (int r = 0; r < 4; ++r) hv[r] = (_Float16)(acc[d][qs][r] * inv);
      *(half4v*)&Od[(size_t)(b * SQ + qw + qs * 16 + lr) * DM + h * DH + d * 16 + lg * 4] = hv;
    }
    if (lg == 0) {
      float2 e; e.x = m_run[qs]; e.y = lt;
      ml[part * (64 * SQ) + ((b * NH + h) * SQ) + qw + qs * 16 + lr] = e;
    }
  }
}

// ---------------- combine partitions (bid<2048) + wo fp32->f16 (bid>=2048) ----------------
__global__ __launch_bounds__(256) void combine_cvt(
    _Float16* __restrict__ AO, const _Float16* __restrict__ O1,
    const float2* __restrict__ ml,
    const float* __restrict__ wo, _Float16* __restrict__ woh)
{
  const int bid = blockIdx.x;
  if (bid < 2048) {
    const int idx = bid * 256 + threadIdx.x;
    const int row = idx >> 8;
    const int col0 = (idx & 255) * 8;
    const int b = row >> 9, q = row & 511, h = col0 >> 7;
    const float2 e0 = ml[(b * NH + h) * SQ + q];
    const float2 e1 = ml[64 * SQ + (b * NH + h) * SQ + q];
    const float m = fmaxf(e0.x, e1.x);
    float w0 = e0.y * exp2f(e0.x - m);
    float w1 = e1.y * exp2f(e1.x - m);
    const float inv = 1.0f / (w0 + w1);
    w0 *= inv; w1 *= inv;
    const size_t o = (size_t)row * DM + col0;
    half8 a = *(const half8*)&AO[o];
    half8 c = *(const half8*)&O1[o];
    half8 r;
#pragma unroll
    for (int i = 0; i < 8; ++i)
      r[i] = (_Float16)(w0 * (float)a[i] + w1 * (float)c[i]);
    *(half8*)&AO[o] = r;
  } else {
    const int cb = bid - 2048;
    const int n4 = DM * DM / 4;
    for (int v = cb * 256 + threadIdx.x; v < n4; v += 512 * 256) {
      float4 x = ((const float4*)wo)[v];
      half4v h = { (_Float16)x.x, (_Float16)x.y, (_Float16)x.z, (_Float16)x.w };
      ((half4v*)woh)[v] = h;
    }
  }
}

extern "C" void kernel_launch(void* const* d_in, const int* in_sizes, int n_in,
                              void* d_out, int out_size, void* d_ws, size_t ws_size,
                              hipStream_t stream) {
  const float* query = (const float*)d_in[0];
  const float* key   = (const float*)d_in[1];
  const float* value = (const float*)d_in[2];
  const float* ck    = (const float*)d_in[3];
  const float* cv    = (const float*)d_in[4];
  const float* wq = (const float*)d_in[5];
  const float* bq = (const float*)d_in[6];
  const float* wk = (const float*)d_in[7];
  const float* bk = (const float*)d_in[8];
  const float* wv = (const float*)d_in[9];
  const float* bv = (const float*)d_in[10];
  const float* wo = (const float*)d_in[11];
  const float* bo = (const float*)d_in[12];

  char* ws = (char*)d_ws;
  _Float16* Kc = (_Float16*)ws;                 // 64 MiB: [4][4096][2048]
  _Float16* Vt = (_Float16*)(ws + 67108864);    // 64 MiB: [4][16][128][4096]
  _Float16* Qp = (_Float16*)(ws + 134217728);   // 8 MiB
  _Float16* AO = (_Float16*)(ws + 142606336);   // 8 MiB

  _Float16* qh = AO;
  _Float16* kh = (_Float16*)d_out;
  _Float16* vh = (_Float16*)((char*)d_out + 8388608);
  _Float16* woh = Qp;  // converted post-attn (Qp dead after attn)

  _Float16* O1s = (_Float16*)d_out;                // 8 MiB
  float2* mls = (float2*)((char*)d_out + 8388608); // 512 KiB

  const long long pb4 = (long long)CL * DM / 4;
  const long long nvec = 4 * pb4;
  const bool huge = ws_size >= (size_t)176160768;               // 168 MiB
  const bool big  = ws_size >= (size_t)153 * 1024 * 1024;

  if (huge) {
    // All weights outside Kc -> ALL convK batches fused; no serial convert_Kpart.
    _Float16* wqh = (_Float16*)(ws + 150994944);   // 144 MiB
    _Float16* wkh = (_Float16*)(ws + 159383552);   // 152 MiB
    _Float16* wvh = (_Float16*)(ws + 167772160);   // 160 MiB
    cvt_f16<<<dim3(512, 6), 256, 0, stream>>>(
        query, key, value, wq, wk, wv, qh, kh, vh, wqh, wkh, wvh);
    fused_pre<<<768 + 3584 + 2048, 512, 0, stream>>>(
        qh, kh, vh, wqh, wkh, wvh, bq, bk, bv, Qp, Kc, Vt, cv, ck, 0);
  } else if (big) {
    // wq outside Kc; wk/wv in Kc b0/b1 cache stripes; convK b2/b3 fused,
    // b0/b1 serial after fused_pre (weights dead by then).
    _Float16* wqh = (_Float16*)(ws + 150994944);
    _Float16* wkh = Kc;
    _Float16* wvh = Kc + (size_t)TT * DM;
    cvt_f16<<<dim3(512, 6), 256, 0, stream>>>(
        query, key, value, wq, wk, wv, qh, kh, vh, wqh, wkh, wvh);
    fused_pre<<<768 + 3584 + 1024, 512, 0, stream>>>(
        qh, kh, vh, wqh, wkh, wvh, bq, bk, bv, Qp, Kc, Vt, cv, ck, 2 * pb4);
    convert_Kpart<<<1024, 256, 0, stream>>>(ck, Kc, 0, 2 * pb4);
  } else {
    // R12 layout: weights in Kc stripes; full convK after fused_pre.
    _Float16* wqh = Kc;
    _Float16* wkh = (_Float16*)(ws + 16777216);
    _Float16* wvh = (_Float16*)(ws + 33554432);
    cvt_f16<<<dim3(512, 6), 256, 0, stream>>>(
        query, key, value, wq, wk, wv, qh, kh, vh, wqh, wkh, wvh);
    fused_pre<<<768 + 3584, 512, 0, stream>>>(
        qh, kh, vh, wqh, wkh, wvh, bq, bk, bv, Qp, Kc, Vt, cv, ck, nvec);
    convert_Kpart<<<2048, 256, 0, stream>>>(ck, Kc, 0, nvec);
  }

  attn_kernel<<<256, 512, 0, stream>>>(Qp, Kc, Vt, AO, O1s, mls);
  combine_cvt<<<2048 + 512, 256, 0, stream>>>(AO, O1s, mls, wo, woh);
  mm16o<<<dim3(16, 32), 512, 0, stream>>>(AO, woh, bo, (float*)d_out);
}